// Round 12
// baseline (70.997 us; speedup 1.0000x reference)
//
#include <hip/hip_runtime.h>
#include <hip/hip_bf16.h>

#define DEV static __device__ __forceinline__

typedef __attribute__((ext_vector_type(8))) short bf16x8;
typedef __attribute__((ext_vector_type(4))) float f32x4;

DEV float sigm(float x) { return 1.0f / (1.0f + __expf(-x)); }

DEV unsigned pack2bf(float a, float b) {
    unsigned ua = __float_as_uint(a); ua = (ua + 0x7FFF + ((ua >> 16) & 1)) >> 16;
    unsigned ub = __float_as_uint(b); ub = (ub + 0x7FFF + ((ub >> 16) & 1)) >> 16;
    return ua | (ub << 16);
}
DEV unsigned short f2bf(float a) {
    unsigned ua = __float_as_uint(a);
    return (unsigned short)((ua + 0x7FFF + ((ua >> 16) & 1)) >> 16);
}
DEV float bfu2f(unsigned short u) { return __uint_as_float(((unsigned)u) << 16); }
DEV float lo2f(unsigned u) { return __uint_as_float(u << 16); }
DEV float hi2f(unsigned u) { return __uint_as_float(u & 0xffff0000u); }

// B=2, N=256, Nh=192, D=128, R=20

// Kernel A: blocks <512: per-atom s_all + x. blocks 512..575: pack mixing weights to bf16.
__global__ __launch_bounds__(256) void kA(
    const float* __restrict__ s_heavy, const int* __restrict__ is_h,
    const float* __restrict__ h_emb, const float* __restrict__ norm1_w,
    const float* __restrict__ W_i1, const float* __restrict__ b_i1,
    const float* __restrict__ W_i2, const float* __restrict__ b_i2,
    const float* __restrict__ W_mu, const float* __restrict__ W_m1,
    const float* __restrict__ W_m2, const float* __restrict__ W_filter,
    const float* __restrict__ b_filter,
    float* __restrict__ s_all, float* __restrict__ x,
    unsigned* __restrict__ Wmu_p, unsigned* __restrict__ Wm1_p,
    unsigned* __restrict__ Wm2_p, unsigned* __restrict__ Wfb_p)
{
    const int blk = blockIdx.x;
    const int t = threadIdx.x;
    if (blk >= 512) {
        const int idx0 = (blk - 512) * 256 + t;       // 0..16383
        {   // W_mu pairs: 64 k2 x 256 c
            int k2 = idx0 >> 8, c = idx0 & 255;
            Wmu_p[idx0] = pack2bf(W_mu[(2 * k2) * 256 + c], W_mu[(2 * k2 + 1) * 256 + c]);
        }
        #pragma unroll
        for (int r = 0; r < 2; ++r) {                 // W_m1 pairs: 128 k2 x 256 c
            int s = idx0 + r * 16384;
            int k2 = s >> 8, c = s & 255;
            Wm1_p[s] = pack2bf(W_m1[(2 * k2) * 256 + c], W_m1[(2 * k2 + 1) * 256 + c]);
        }
        for (int s = idx0; s < 24576; s += 16384) {   // W_m2 pairs: 64 k2 x 384 c
            int k2 = s / 384, c = s - k2 * 384;
            Wm2_p[s] = pack2bf(W_m2[(2 * k2) * 384 + c], W_m2[(2 * k2 + 1) * 384 + c]);
        }
        for (int s = idx0; s < 4032; s += 16384) {    // [W_filter(7680) | b_filter(384)] u16
            int e = 2 * s;
            float v0 = (e < 7680) ? W_filter[e] : b_filter[e - 7680];
            float v1 = (e + 1 < 7680) ? W_filter[e + 1] : b_filter[e + 1 - 7680];
            Wfb_p[s] = pack2bf(v0, v1);
        }
        return;
    }
    const int bi = blk;
    const int b = bi >> 8, i = bi & 255;
    __shared__ float y[128];
    __shared__ float o[256];
    __shared__ float h[128];
    __shared__ float red[4];

    float s = 0.f;
    if (t < 128) {
        if (is_h[bi] != 0) s = h_emb[t];
        else if (i < 192) s = s_heavy[(b * 192 + i) * 128 + t];
        s_all[bi * 128 + t] = s;
    }
    float ss = s * s;
    #pragma unroll
    for (int off = 32; off > 0; off >>= 1) ss += __shfl_xor(ss, off, 64);
    if ((t & 63) == 0) red[t >> 6] = ss;
    __syncthreads();
    float v = (red[0] + red[1] + red[2] + red[3]) * (1.0f / 128.0f);
    float inv = rsqrtf(v + 1e-6f);
    if (t < 128) y[t] = s * inv * (1.0f + norm1_w[t]);
    __syncthreads();

    float acc = b_i1[t];
    #pragma unroll 8
    for (int k = 0; k < 128; ++k) acc += y[k] * W_i1[k * 256 + t];
    o[t] = acc;
    __syncthreads();
    if (t < 128) {
        float a = o[t], g = o[t + 128];
        h[t] = a * sigm(a) * sigm(g);
    }
    __syncthreads();
    for (int c = t; c < 384; c += 256) {
        float a2 = b_i2[c];
        #pragma unroll 8
        for (int k = 0; k < 128; ++k) a2 += h[k] * W_i2[k * 384 + c];
        x[(long)bi * 384 + c] = a2;
    }
}

// Kernel X2: build frag-contiguous B panel (uint4 per (b,kt,g,col) = 8 bf16 along j).
__global__ __launch_bounds__(640) void kX2(
    const float* __restrict__ x, const float* __restrict__ v_all,
    unsigned* __restrict__ Bg)
{
    int blk = blockIdx.x;
    const int g = blk & 3; blk >>= 2;
    const int kt = blk & 7; const int b = blk >> 3;
    const int col = threadIdx.x;
    const int j0 = kt * 32 + g * 8;
    const float* xb = x + (long)b * 98304;
    const float* vb = v_all + (long)b * 98304;

    float vals[8];
    if (col < 256) {
        #pragma unroll
        for (int jj = 0; jj < 8; ++jj) vals[jj] = xb[(j0 + jj) * 384 + col];
    } else {
        const int cg = col - 256, r3 = cg >> 7, c3 = cg & 127;
        #pragma unroll
        for (int jj = 0; jj < 8; ++jj) {
            const int j = j0 + jj;
            vals[jj] = vb[j * 384 + r3 * 128 + c3] * xb[j * 384 + 256 + c3];
        }
    }
    uint4 outv = make_uint4(pack2bf(vals[0], vals[1]), pack2bf(vals[2], vals[3]),
                            pack2bf(vals[4], vals[5]), pack2bf(vals[6], vals[7]));
    *(uint4*)&Bg[(((long)(b * 8 + kt) * 4 + g) * 640 + col) * 4] = outv;
}

// Kernel BC (fused B+C), 53248 B LDS -> 3 blocks/CU:
//  Phase B: A (96x256 bf16, built fused with rbf staging) @ Bg via MFMA; Wf contraction.
//  Phase C: mixing with bf16-packed weights (temps aliased onto dead A16).
__global__ __launch_bounds__(512, 6) void kBC(
    const float* __restrict__ rbf, const float* __restrict__ dir_ij,
    const float* __restrict__ mask_ij, const float* __restrict__ v_all,
    const float* __restrict__ s_all, const unsigned* __restrict__ Bg,
    const unsigned* __restrict__ Wmu_p, const float* __restrict__ norm2_w,
    const unsigned* __restrict__ Wm1_p, const float* __restrict__ b_m1,
    const unsigned* __restrict__ Wm2_p, const float* __restrict__ b_m2,
    const unsigned* __restrict__ Wfb_p,
    float* __restrict__ q_out, float* __restrict__ mu_out)
{
    const int bi = blockIdx.x, b = bi >> 8, i = bi & 255;
    const int t = threadIdx.x;
    const int lane = t & 63, w = t >> 6, g = lane >> 4, l16 = lane & 15;

    __shared__ __align__(16) unsigned short A16[96 * 264];  // 50688 B
    __shared__ unsigned short dir16[768];                   // 1536 B
    __shared__ float m_s[256];                              // 1024 B

    // ---- pass 1: stage m, dir16 (bf16); zero pad rows 21-31, 95 ----
    if (t < 256) m_s[t] = mask_ij[(long)bi * 256 + t];
    for (int idx = t; idx < 768; idx += 512) dir16[idx] = f2bf(dir_ij[(long)bi * 768 + idx]);
    {
        unsigned* Az = (unsigned*)A16;
        for (int s2 = t; s2 < 1452; s2 += 512) Az[2772 + s2] = 0;   // rows 21-31
        if (t < 132) Az[12540 + t] = 0;                              // row 95
    }
    __syncthreads();

    // ---- pass 2: fused rbf load + A build (rows r, 32+r, 53+r, 74+r) ----
    for (int i2 = t; i2 < 5120; i2 += 512) {
        const int j = i2 / 20, r = i2 - j * 20;
        const float vm = rbf[(long)bi * 5120 + i2] * m_s[j];
        const float d0 = bfu2f(dir16[j * 3 + 0]);
        const float d1 = bfu2f(dir16[j * 3 + 1]);
        const float d2 = bfu2f(dir16[j * 3 + 2]);
        A16[r * 264 + j] = f2bf(vm);
        A16[(32 + r) * 264 + j] = f2bf(vm * d0);
        A16[(53 + r) * 264 + j] = f2bf(vm * d1);
        A16[(74 + r) * 264 + j] = f2bf(vm * d2);
    }
    if (t < 256) {   // mask rows: 20, 52, 73, 94
        const int j = t;
        const float m = m_s[j];
        A16[20 * 264 + j] = f2bf(m);
        A16[52 * 264 + j] = f2bf(m * bfu2f(dir16[j * 3 + 0]));
        A16[73 * 264 + j] = f2bf(m * bfu2f(dir16[j * 3 + 1]));
        A16[94 * 264 + j] = f2bf(m * bfu2f(dir16[j * 3 + 2]));
    }
    __syncthreads();

    // ---- tile assignment ----
    int colR[4];
    #pragma unroll
    for (int ci = 0; ci < 4; ++ci) {
        int ct = (w < 2) ? (4 * w + ci) : (4 * w + 8 + ci);
        colR[ci] = ct * 16 + l16;
    }
    const int col2 = (8 + w) * 16 + l16;

    const unsigned* BgB = Bg + (long)b * 81920;
    const unsigned short* Wfb16 = (const unsigned short*)Wfb_p;

    f32x4 accR[4][2];
    f32x4 acc2[4];
    #pragma unroll
    for (int ci = 0; ci < 4; ++ci) {
        #pragma unroll
        for (int rt = 0; rt < 2; ++rt) accR[ci][rt] = {0.f, 0.f, 0.f, 0.f};
        acc2[ci] = {0.f, 0.f, 0.f, 0.f};
    }

    // ---- GEMM: K = 256 j = 8 k-steps of 32 ----
    #pragma unroll 2
    for (int kt = 0; kt < 8; ++kt) {
        bf16x8 af[6];
        #pragma unroll
        for (int rt = 0; rt < 6; ++rt)
            af[rt] = *(const bf16x8*)&A16[(rt * 16 + l16) * 264 + kt * 32 + g * 8];
        const unsigned* Bk = BgB + ((long)kt * 4 + g) * 640 * 4;
        bf16x8 bfr[5];
        #pragma unroll
        for (int u = 0; u < 4; ++u)
            bfr[u] = *(const bf16x8*)&Bk[colR[u] * 4];
        bfr[4] = *(const bf16x8*)&Bk[col2 * 4];
        #pragma unroll
        for (int ci = 0; ci < 4; ++ci) {
            accR[ci][0] = __builtin_amdgcn_mfma_f32_16x16x32_bf16(af[0], bfr[ci], accR[ci][0], 0, 0, 0);
            accR[ci][1] = __builtin_amdgcn_mfma_f32_16x16x32_bf16(af[1], bfr[ci], accR[ci][1], 0, 0, 0);
        }
        #pragma unroll
        for (int rt = 0; rt < 4; ++rt)
            acc2[rt] = __builtin_amdgcn_mfma_f32_16x16x32_bf16(af[2 + rt], bfr[4], acc2[rt], 0, 0, 0);
    }
    __syncthreads();   // A16 dead from here; aliases below are safe

    // ---- aliased LDS buffers on A16 (12672 f32 available) ----
    float* fb      = (float*)A16;
    float* dmuR_s  = fb;           // 384
    float* dmumu_s = fb + 384;     // 384
    float* q_s     = fb + 768;     // 128
    float* mu_s    = fb + 896;     // 384
    float* part    = fb + 1280;    // [2][768]
    float* muV     = fb + 2816;    // 384
    float* muW     = fb + 3200;    // 384
    float* ctx     = fb + 3584;    // 256
    float* o_part  = fb + 3840;    // [2][256]
    float* hsm     = fb + 4352;    // 128
    float* x2s     = fb + 4480;    // 384
    float* red     = fb + 4864;    // 8

    // ---- epilogue T2 -> dmuR_s ----
    {
        float p3[3] = {0.f, 0.f, 0.f};
        const int c = 128 + 16 * w + l16;
        #pragma unroll
        for (int rt = 0; rt < 4; ++rt) {
            #pragma unroll
            for (int e = 0; e < 4; ++e) {
                int l = rt * 16 + g * 4 + e;
                if (l < 63) {
                    int r3 = (l >= 42) ? 2 : ((l >= 21) ? 1 : 0);
                    int rr = l - 21 * r3;
                    float wgt = bfu2f((rr < 20) ? Wfb16[rr * 384 + c] : Wfb16[7680 + c]);
                    p3[r3] += wgt * acc2[rt][e];
                }
            }
        }
        #pragma unroll
        for (int r3 = 0; r3 < 3; ++r3) {
            float a = p3[r3];
            a += __shfl_xor(a, 16, 64);
            a += __shfl_xor(a, 32, 64);
            if (lane < 16) dmuR_s[r3 * 128 + 16 * w + l16] = a;
        }
    }

    // ---- epilogue T1/T3 -> q_s / dmumu_s ----
    #pragma unroll
    for (int ci = 0; ci < 4; ++ci) {
        const int cwf = (w < 2) ? colR[ci] : (256 + ((colR[ci] - 256) & 127));
        float p = 0.f;
        #pragma unroll
        for (int rt = 0; rt < 2; ++rt) {
            #pragma unroll
            for (int e = 0; e < 4; ++e) {
                int row = rt * 16 + g * 4 + e;
                if (row <= 20) {
                    float wgt = bfu2f((row < 20) ? Wfb16[row * 384 + cwf] : Wfb16[7680 + cwf]);
                    p += wgt * accR[ci][rt][e];
                }
            }
        }
        p += __shfl_xor(p, 16, 64);
        p += __shfl_xor(p, 32, 64);
        if (lane < 16) {
            if (w < 2) {
                int c = colR[ci];
                q_s[c] = s_all[bi * 128 + c] + p;
            } else {
                dmumu_s[colR[ci] - 256] = p;
            }
        }
    }
    __syncthreads();
    for (int e2 = t; e2 < 384; e2 += 512)
        mu_s[e2] = v_all[(long)bi * 384 + e2] + dmuR_s[e2] + dmumu_s[e2];
    __syncthreads();

    // ================= Phase C: mixing =================
    const int c = t & 255, kh = t >> 8;
    float qv = (t < 128) ? q_s[t] : 0.f;

    // mu_mix (split-K halves, packed pairs along k)
    {
        float m0 = 0.f, m1 = 0.f, m2 = 0.f;
        const int k20 = kh * 32;
        #pragma unroll 8
        for (int k2 = k20; k2 < k20 + 32; ++k2) {
            unsigned u = Wmu_p[k2 * 256 + c];
            float w0 = lo2f(u), w1 = hi2f(u);
            m0 += mu_s[2 * k2] * w0 + mu_s[2 * k2 + 1] * w1;
            m1 += mu_s[128 + 2 * k2] * w0 + mu_s[128 + 2 * k2 + 1] * w1;
            m2 += mu_s[256 + 2 * k2] * w0 + mu_s[256 + 2 * k2 + 1] * w1;
        }
        part[kh * 768 + c] = m0; part[kh * 768 + 256 + c] = m1; part[kh * 768 + 512 + c] = m2;
    }
    float ss = qv * qv;
    #pragma unroll
    for (int off = 32; off > 0; off >>= 1) ss += __shfl_xor(ss, off, 64);
    if ((t & 63) == 0) red[t >> 6] = ss;
    __syncthreads();
    for (int idx = t; idx < 768; idx += 512) {
        const int r3 = idx >> 8, cc = idx & 255;
        float val = part[idx] + part[768 + idx];
        if (cc < 128) muV[r3 * 128 + cc] = val;
        else          muW[r3 * 128 + (cc - 128)] = val;
    }
    __syncthreads();
    float mean = (red[0] + red[1] + red[2] + red[3] + red[4] + red[5] + red[6] + red[7])
                 * (1.0f / 128.0f);
    if (t < 128) {
        ctx[t] = qv * rsqrtf(mean + 1e-6f) * (1.0f + norm2_w[t]);
    } else if (t < 256) {
        int d2 = t - 128;
        ctx[t] = sqrtf(muV[d2] * muV[d2] + muV[128 + d2] * muV[128 + d2]
                       + muV[256 + d2] * muV[256 + d2] + 1e-6f);
    }
    __syncthreads();

    // o = ctx @ W_m1 (split-K halves, packed, dual accumulators)
    {
        float acc0 = 0.f, acc1 = 0.f;
        const int k20 = kh * 64;
        #pragma unroll 8
        for (int k2 = k20; k2 < k20 + 64; k2 += 2) {
            unsigned u0 = Wm1_p[k2 * 256 + c];
            unsigned u1 = Wm1_p[(k2 + 1) * 256 + c];
            acc0 += ctx[2 * k2] * lo2f(u0) + ctx[2 * k2 + 1] * hi2f(u0);
            acc1 += ctx[2 * k2 + 2] * lo2f(u1) + ctx[2 * k2 + 3] * hi2f(u1);
        }
        o_part[kh * 256 + c] = acc0 + acc1;
    }
    __syncthreads();
    if (t < 128) {
        float a  = o_part[t]       + o_part[256 + t]       + b_m1[t];
        float gg = o_part[t + 128] + o_part[256 + t + 128] + b_m1[t + 128];
        hsm[t] = a * sigm(a) * sigm(gg);
    }
    __syncthreads();
    if (t < 384) {
        float a0 = b_m2[t], a1 = 0.f;
        #pragma unroll 8
        for (int k2 = 0; k2 < 64; k2 += 2) {
            unsigned u0 = Wm2_p[k2 * 384 + t];
            unsigned u1 = Wm2_p[(k2 + 1) * 384 + t];
            a0 += hsm[2 * k2] * lo2f(u0) + hsm[2 * k2 + 1] * hi2f(u0);
            a1 += hsm[2 * k2 + 2] * lo2f(u1) + hsm[2 * k2 + 3] * hi2f(u1);
        }
        x2s[t] = a0 + a1;
    }
    __syncthreads();

    if (t < 128) {
        const int d = t;
        float vw = muV[d] * muW[d] + muV[128 + d] * muW[128 + d] + muV[256 + d] * muW[256 + d];
        if (i < 192)
            q_out[((long)b * 192 + i) * 128 + d] = qv + x2s[d] + x2s[256 + d] * vw;
        #pragma unroll
        for (int r = 0; r < 3; ++r)
            mu_out[((long)bi * 3 + r) * 128 + d] =
                mu_s[r * 128 + d] + x2s[128 + d] * muW[r * 128 + d];
    }
}

extern "C" void kernel_launch(void* const* d_in, const int* in_sizes, int n_in,
                              void* d_out, int out_size, void* d_ws, size_t ws_size,
                              hipStream_t stream) {
    (void)in_sizes; (void)n_in; (void)out_size;
    const float* s_heavy  = (const float*)d_in[0];
    const float* v_all    = (const float*)d_in[1];
    const float* rbf      = (const float*)d_in[2];
    const float* dir_ij   = (const float*)d_in[3];
    const float* mask_ij  = (const float*)d_in[4];
    const int*   is_h     = (const int*)d_in[5];
    const float* h_emb    = (const float*)d_in[6];
    const float* W_filter = (const float*)d_in[7];
    const float* b_filter = (const float*)d_in[8];
    const float* norm1_w  = (const float*)d_in[9];
    const float* W_i1     = (const float*)d_in[10];
    const float* b_i1     = (const float*)d_in[11];
    const float* W_i2     = (const float*)d_in[12];
    const float* b_i2     = (const float*)d_in[13];
    const float* norm2_w  = (const float*)d_in[14];
    const float* W_m1     = (const float*)d_in[15];
    const float* b_m1     = (const float*)d_in[16];
    const float* W_m2     = (const float*)d_in[17];
    const float* b_m2     = (const float*)d_in[18];
    const float* W_mu     = (const float*)d_in[19];

    // ws layout (f32 units): s_all 0 | x 65536 | Bg 262144(+163840) | Wmu_p 425984(+16384)
    //  | Wm1_p 442368(+32768) | Wm2_p 475136(+24576) | Wfb_p 499712(+4032)
    const size_t need = (size_t)503744 * 4;
    if (ws_size < need) return;
    float* ws    = (float*)d_ws;
    float* s_all = ws;
    float* x     = ws + 65536;
    unsigned* Bg    = (unsigned*)(ws + 262144);
    unsigned* Wmu_p = (unsigned*)(ws + 425984);
    unsigned* Wm1_p = (unsigned*)(ws + 442368);
    unsigned* Wm2_p = (unsigned*)(ws + 475136);
    unsigned* Wfb_p = (unsigned*)(ws + 499712);

    float* q_out  = (float*)d_out;               // (2,192,128)
    float* mu_out = q_out + 2 * 192 * 128;       // (2,256,3,128)

    kA<<<576, 256, 0, stream>>>(s_heavy, is_h, h_emb, norm1_w, W_i1, b_i1, W_i2, b_i2,
                                W_mu, W_m1, W_m2, W_filter, b_filter,
                                s_all, x, Wmu_p, Wm1_p, Wm2_p, Wfb_p);
    kX2<<<64, 640, 0, stream>>>(x, v_all, Bg);
    kBC<<<512, 512, 0, stream>>>(rbf, dir_ij, mask_ij, v_all, s_all, Bg,
                                 Wmu_p, norm2_w, Wm1_p, b_m1, Wm2_p, b_m2, Wfb_p,
                                 q_out, mu_out);
}

// Round 13
// 50.506 us; speedup vs baseline: 1.4057x; 1.4057x over previous
//
#include <hip/hip_runtime.h>
#include <hip/hip_bf16.h>

#define DEV static __device__ __forceinline__

typedef __attribute__((ext_vector_type(8))) short bf16x8;
typedef __attribute__((ext_vector_type(4))) float f32x4;

DEV float sigm(float x) { return 1.0f / (1.0f + __expf(-x)); }

DEV unsigned pack2bf(float a, float b) {
    unsigned ua = __float_as_uint(a); ua = (ua + 0x7FFF + ((ua >> 16) & 1)) >> 16;
    unsigned ub = __float_as_uint(b); ub = (ub + 0x7FFF + ((ub >> 16) & 1)) >> 16;
    return ua | (ub << 16);
}
DEV unsigned short f2bf(float a) {
    unsigned ua = __float_as_uint(a);
    return (unsigned short)((ua + 0x7FFF + ((ua >> 16) & 1)) >> 16);
}
DEV float bfu2f(unsigned short u) { return __uint_as_float(((unsigned)u) << 16); }
DEV float lo2f(unsigned u) { return __uint_as_float(u << 16); }
DEV float hi2f(unsigned u) { return __uint_as_float(u & 0xffff0000u); }

// B=2, N=256, Nh=192, D=128, R=20

// Kernel A: blocks <512: per-atom s_all + x. blocks 512..575: pack mixing weights to bf16.
__global__ __launch_bounds__(256) void kA(
    const float* __restrict__ s_heavy, const int* __restrict__ is_h,
    const float* __restrict__ h_emb, const float* __restrict__ norm1_w,
    const float* __restrict__ W_i1, const float* __restrict__ b_i1,
    const float* __restrict__ W_i2, const float* __restrict__ b_i2,
    const float* __restrict__ W_mu, const float* __restrict__ W_m1,
    const float* __restrict__ W_m2, const float* __restrict__ W_filter,
    const float* __restrict__ b_filter,
    float* __restrict__ s_all, float* __restrict__ x,
    unsigned* __restrict__ Wmu_p, unsigned* __restrict__ Wm1_p,
    unsigned* __restrict__ Wm2_p, unsigned* __restrict__ Wfb_p)
{
    const int blk = blockIdx.x;
    const int t = threadIdx.x;
    if (blk >= 512) {
        const int idx0 = (blk - 512) * 256 + t;       // 0..16383
        {   // W_mu pairs: 64 k2 x 256 c
            int k2 = idx0 >> 8, c = idx0 & 255;
            Wmu_p[idx0] = pack2bf(W_mu[(2 * k2) * 256 + c], W_mu[(2 * k2 + 1) * 256 + c]);
        }
        #pragma unroll
        for (int r = 0; r < 2; ++r) {                 // W_m1 pairs: 128 k2 x 256 c
            int s = idx0 + r * 16384;
            int k2 = s >> 8, c = s & 255;
            Wm1_p[s] = pack2bf(W_m1[(2 * k2) * 256 + c], W_m1[(2 * k2 + 1) * 256 + c]);
        }
        for (int s = idx0; s < 24576; s += 16384) {   // W_m2 pairs: 64 k2 x 384 c
            int k2 = s / 384, c = s - k2 * 384;
            Wm2_p[s] = pack2bf(W_m2[(2 * k2) * 384 + c], W_m2[(2 * k2 + 1) * 384 + c]);
        }
        for (int s = idx0; s < 4032; s += 16384) {    // [W_filter(7680) | b_filter(384)] u16
            int e = 2 * s;
            float v0 = (e < 7680) ? W_filter[e] : b_filter[e - 7680];
            float v1 = (e + 1 < 7680) ? W_filter[e + 1] : b_filter[e + 1 - 7680];
            Wfb_p[s] = pack2bf(v0, v1);
        }
        return;
    }
    const int bi = blk;
    const int b = bi >> 8, i = bi & 255;
    __shared__ float y[128];
    __shared__ float o[256];
    __shared__ float h[128];
    __shared__ float red[4];

    float s = 0.f;
    if (t < 128) {
        if (is_h[bi] != 0) s = h_emb[t];
        else if (i < 192) s = s_heavy[(b * 192 + i) * 128 + t];
        s_all[bi * 128 + t] = s;
    }
    float ss = s * s;
    #pragma unroll
    for (int off = 32; off > 0; off >>= 1) ss += __shfl_xor(ss, off, 64);
    if ((t & 63) == 0) red[t >> 6] = ss;
    __syncthreads();
    float v = (red[0] + red[1] + red[2] + red[3]) * (1.0f / 128.0f);
    float inv = rsqrtf(v + 1e-6f);
    if (t < 128) y[t] = s * inv * (1.0f + norm1_w[t]);
    __syncthreads();

    float acc = b_i1[t];
    #pragma unroll 8
    for (int k = 0; k < 128; ++k) acc += y[k] * W_i1[k * 256 + t];
    o[t] = acc;
    __syncthreads();
    if (t < 128) {
        float a = o[t], g = o[t + 128];
        h[t] = a * sigm(a) * sigm(g);
    }
    __syncthreads();
    for (int c = t; c < 384; c += 256) {
        float a2 = b_i2[c];
        #pragma unroll 8
        for (int k = 0; k < 128; ++k) a2 += h[k] * W_i2[k * 384 + c];
        x[(long)bi * 384 + c] = a2;
    }
}

// Kernel X2: build frag-contiguous B panel (uint4 per (b,kt,g,col) = 8 bf16 along j).
__global__ __launch_bounds__(640) void kX2(
    const float* __restrict__ x, const float* __restrict__ v_all,
    unsigned* __restrict__ Bg)
{
    int blk = blockIdx.x;
    const int g = blk & 3; blk >>= 2;
    const int kt = blk & 7; const int b = blk >> 3;
    const int col = threadIdx.x;
    const int j0 = kt * 32 + g * 8;
    const float* xb = x + (long)b * 98304;
    const float* vb = v_all + (long)b * 98304;

    float vals[8];
    if (col < 256) {
        #pragma unroll
        for (int jj = 0; jj < 8; ++jj) vals[jj] = xb[(j0 + jj) * 384 + col];
    } else {
        const int cg = col - 256, r3 = cg >> 7, c3 = cg & 127;
        #pragma unroll
        for (int jj = 0; jj < 8; ++jj) {
            const int j = j0 + jj;
            vals[jj] = vb[j * 384 + r3 * 128 + c3] * xb[j * 384 + 256 + c3];
        }
    }
    uint4 outv = make_uint4(pack2bf(vals[0], vals[1]), pack2bf(vals[2], vals[3]),
                            pack2bf(vals[4], vals[5]), pack2bf(vals[6], vals[7]));
    *(uint4*)&Bg[(((long)(b * 8 + kt) * 4 + g) * 640 + col) * 4] = outv;
}

// Kernel BC (fused B+C), 53248 B LDS; launch_bounds(512,4) -> compiler ~64 VGPR (no spill),
// HW occupancy = min(VGPR 4, LDS 3) = 3 blocks/CU.
__global__ __launch_bounds__(512, 4) void kBC(
    const float* __restrict__ rbf, const float* __restrict__ dir_ij,
    const float* __restrict__ mask_ij, const float* __restrict__ v_all,
    const float* __restrict__ s_all, const unsigned* __restrict__ Bg,
    const unsigned* __restrict__ Wmu_p, const float* __restrict__ norm2_w,
    const unsigned* __restrict__ Wm1_p, const float* __restrict__ b_m1,
    const unsigned* __restrict__ Wm2_p, const float* __restrict__ b_m2,
    const unsigned* __restrict__ Wfb_p,
    float* __restrict__ q_out, float* __restrict__ mu_out)
{
    const int bi = blockIdx.x, b = bi >> 8, i = bi & 255;
    const int t = threadIdx.x;
    const int lane = t & 63, w = t >> 6, g = lane >> 4, l16 = lane & 15;

    __shared__ __align__(16) unsigned short A16[96 * 264];  // 50688 B
    __shared__ unsigned short dir16[768];                   // 1536 B
    __shared__ float m_s[256];                              // 1024 B

    // ---- pass 1: stage m, dir16 (bf16); zero pad rows 21-31, 95 ----
    if (t < 256) m_s[t] = mask_ij[(long)bi * 256 + t];
    for (int idx = t; idx < 768; idx += 512) dir16[idx] = f2bf(dir_ij[(long)bi * 768 + idx]);
    {
        unsigned* Az = (unsigned*)A16;
        for (int s2 = t; s2 < 1452; s2 += 512) Az[2772 + s2] = 0;   // rows 21-31
        if (t < 132) Az[12540 + t] = 0;                              // row 95
    }
    __syncthreads();

    // ---- pass 2: fused rbf load + A build (rows r, 32+r, 53+r, 74+r) ----
    for (int i2 = t; i2 < 5120; i2 += 512) {
        const int j = i2 / 20, r = i2 - j * 20;
        const float vm = rbf[(long)bi * 5120 + i2] * m_s[j];
        const float d0 = bfu2f(dir16[j * 3 + 0]);
        const float d1 = bfu2f(dir16[j * 3 + 1]);
        const float d2 = bfu2f(dir16[j * 3 + 2]);
        A16[r * 264 + j] = f2bf(vm);
        A16[(32 + r) * 264 + j] = f2bf(vm * d0);
        A16[(53 + r) * 264 + j] = f2bf(vm * d1);
        A16[(74 + r) * 264 + j] = f2bf(vm * d2);
    }
    if (t < 256) {   // mask rows: 20, 52, 73, 94
        const int j = t;
        const float m = m_s[j];
        A16[20 * 264 + j] = f2bf(m);
        A16[52 * 264 + j] = f2bf(m * bfu2f(dir16[j * 3 + 0]));
        A16[73 * 264 + j] = f2bf(m * bfu2f(dir16[j * 3 + 1]));
        A16[94 * 264 + j] = f2bf(m * bfu2f(dir16[j * 3 + 2]));
    }
    __syncthreads();

    // ---- tile assignment ----
    int colR[4];
    #pragma unroll
    for (int ci = 0; ci < 4; ++ci) {
        int ct = (w < 2) ? (4 * w + ci) : (4 * w + 8 + ci);
        colR[ci] = ct * 16 + l16;
    }
    const int col2 = (8 + w) * 16 + l16;

    const unsigned* BgB = Bg + (long)b * 81920;
    const unsigned short* Wfb16 = (const unsigned short*)Wfb_p;

    f32x4 accR[4][2];
    f32x4 acc2[4];
    #pragma unroll
    for (int ci = 0; ci < 4; ++ci) {
        #pragma unroll
        for (int rt = 0; rt < 2; ++rt) accR[ci][rt] = {0.f, 0.f, 0.f, 0.f};
        acc2[ci] = {0.f, 0.f, 0.f, 0.f};
    }

    // ---- GEMM: K = 256 j = 8 k-steps of 32 ----
    #pragma unroll 2
    for (int kt = 0; kt < 8; ++kt) {
        bf16x8 af[6];
        #pragma unroll
        for (int rt = 0; rt < 6; ++rt)
            af[rt] = *(const bf16x8*)&A16[(rt * 16 + l16) * 264 + kt * 32 + g * 8];
        const unsigned* Bk = BgB + ((long)kt * 4 + g) * 640 * 4;
        bf16x8 bfr[5];
        #pragma unroll
        for (int u = 0; u < 4; ++u)
            bfr[u] = *(const bf16x8*)&Bk[colR[u] * 4];
        bfr[4] = *(const bf16x8*)&Bk[col2 * 4];
        #pragma unroll
        for (int ci = 0; ci < 4; ++ci) {
            accR[ci][0] = __builtin_amdgcn_mfma_f32_16x16x32_bf16(af[0], bfr[ci], accR[ci][0], 0, 0, 0);
            accR[ci][1] = __builtin_amdgcn_mfma_f32_16x16x32_bf16(af[1], bfr[ci], accR[ci][1], 0, 0, 0);
        }
        #pragma unroll
        for (int rt = 0; rt < 4; ++rt)
            acc2[rt] = __builtin_amdgcn_mfma_f32_16x16x32_bf16(af[2 + rt], bfr[4], acc2[rt], 0, 0, 0);
    }
    __syncthreads();   // A16 dead from here; aliases below are safe

    // ---- aliased LDS buffers on A16 (12672 f32 available) ----
    float* fb      = (float*)A16;
    float* dmuR_s  = fb;           // 384
    float* dmumu_s = fb + 384;     // 384
    float* q_s     = fb + 768;     // 128
    float* mu_s    = fb + 896;     // 384
    float* part    = fb + 1280;    // [2][768]
    float* muV     = fb + 2816;    // 384
    float* muW     = fb + 3200;    // 384
    float* ctx     = fb + 3584;    // 256
    float* o_part  = fb + 3840;    // [2][256]
    float* hsm     = fb + 4352;    // 128
    float* x2s     = fb + 4480;    // 384
    float* red     = fb + 4864;    // 8

    // ---- epilogue T2 -> dmuR_s ----
    {
        float p3[3] = {0.f, 0.f, 0.f};
        const int c = 128 + 16 * w + l16;
        #pragma unroll
        for (int rt = 0; rt < 4; ++rt) {
            #pragma unroll
            for (int e = 0; e < 4; ++e) {
                int l = rt * 16 + g * 4 + e;
                if (l < 63) {
                    int r3 = (l >= 42) ? 2 : ((l >= 21) ? 1 : 0);
                    int rr = l - 21 * r3;
                    float wgt = bfu2f((rr < 20) ? Wfb16[rr * 384 + c] : Wfb16[7680 + c]);
                    p3[r3] += wgt * acc2[rt][e];
                }
            }
        }
        #pragma unroll
        for (int r3 = 0; r3 < 3; ++r3) {
            float a = p3[r3];
            a += __shfl_xor(a, 16, 64);
            a += __shfl_xor(a, 32, 64);
            if (lane < 16) dmuR_s[r3 * 128 + 16 * w + l16] = a;
        }
    }

    // ---- epilogue T1/T3 -> q_s / dmumu_s ----
    #pragma unroll
    for (int ci = 0; ci < 4; ++ci) {
        const int cwf = (w < 2) ? colR[ci] : (256 + ((colR[ci] - 256) & 127));
        float p = 0.f;
        #pragma unroll
        for (int rt = 0; rt < 2; ++rt) {
            #pragma unroll
            for (int e = 0; e < 4; ++e) {
                int row = rt * 16 + g * 4 + e;
                if (row <= 20) {
                    float wgt = bfu2f((row < 20) ? Wfb16[row * 384 + cwf] : Wfb16[7680 + cwf]);
                    p += wgt * accR[ci][rt][e];
                }
            }
        }
        p += __shfl_xor(p, 16, 64);
        p += __shfl_xor(p, 32, 64);
        if (lane < 16) {
            if (w < 2) {
                int c = colR[ci];
                q_s[c] = s_all[bi * 128 + c] + p;
            } else {
                dmumu_s[colR[ci] - 256] = p;
            }
        }
    }
    __syncthreads();
    for (int e2 = t; e2 < 384; e2 += 512)
        mu_s[e2] = v_all[(long)bi * 384 + e2] + dmuR_s[e2] + dmumu_s[e2];
    __syncthreads();

    // ================= Phase C: mixing =================
    const int c = t & 255, kh = t >> 8;
    float qv = (t < 128) ? q_s[t] : 0.f;

    // mu_mix (split-K halves, packed pairs along k)
    {
        float m0 = 0.f, m1 = 0.f, m2 = 0.f;
        const int k20 = kh * 32;
        #pragma unroll 8
        for (int k2 = k20; k2 < k20 + 32; ++k2) {
            unsigned u = Wmu_p[k2 * 256 + c];
            float w0 = lo2f(u), w1 = hi2f(u);
            m0 += mu_s[2 * k2] * w0 + mu_s[2 * k2 + 1] * w1;
            m1 += mu_s[128 + 2 * k2] * w0 + mu_s[128 + 2 * k2 + 1] * w1;
            m2 += mu_s[256 + 2 * k2] * w0 + mu_s[256 + 2 * k2 + 1] * w1;
        }
        part[kh * 768 + c] = m0; part[kh * 768 + 256 + c] = m1; part[kh * 768 + 512 + c] = m2;
    }
    float ss = qv * qv;
    #pragma unroll
    for (int off = 32; off > 0; off >>= 1) ss += __shfl_xor(ss, off, 64);
    if ((t & 63) == 0) red[t >> 6] = ss;
    __syncthreads();
    for (int idx = t; idx < 768; idx += 512) {
        const int r3 = idx >> 8, cc = idx & 255;
        float val = part[idx] + part[768 + idx];
        if (cc < 128) muV[r3 * 128 + cc] = val;
        else          muW[r3 * 128 + (cc - 128)] = val;
    }
    __syncthreads();
    float mean = (red[0] + red[1] + red[2] + red[3] + red[4] + red[5] + red[6] + red[7])
                 * (1.0f / 128.0f);
    if (t < 128) {
        ctx[t] = qv * rsqrtf(mean + 1e-6f) * (1.0f + norm2_w[t]);
    } else if (t < 256) {
        int d2 = t - 128;
        ctx[t] = sqrtf(muV[d2] * muV[d2] + muV[128 + d2] * muV[128 + d2]
                       + muV[256 + d2] * muV[256 + d2] + 1e-6f);
    }
    __syncthreads();

    // o = ctx @ W_m1 (split-K halves, packed, dual accumulators)
    {
        float acc0 = 0.f, acc1 = 0.f;
        const int k20 = kh * 64;
        #pragma unroll 8
        for (int k2 = k20; k2 < k20 + 64; k2 += 2) {
            unsigned u0 = Wm1_p[k2 * 256 + c];
            unsigned u1 = Wm1_p[(k2 + 1) * 256 + c];
            acc0 += ctx[2 * k2] * lo2f(u0) + ctx[2 * k2 + 1] * hi2f(u0);
            acc1 += ctx[2 * k2 + 2] * lo2f(u1) + ctx[2 * k2 + 3] * hi2f(u1);
        }
        o_part[kh * 256 + c] = acc0 + acc1;
    }
    __syncthreads();
    if (t < 128) {
        float a  = o_part[t]       + o_part[256 + t]       + b_m1[t];
        float gg = o_part[t + 128] + o_part[256 + t + 128] + b_m1[t + 128];
        hsm[t] = a * sigm(a) * sigm(gg);
    }
    __syncthreads();
    if (t < 384) {
        float a0 = b_m2[t], a1 = 0.f;
        #pragma unroll 8
        for (int k2 = 0; k2 < 64; k2 += 2) {
            unsigned u0 = Wm2_p[k2 * 384 + t];
            unsigned u1 = Wm2_p[(k2 + 1) * 384 + t];
            a0 += hsm[2 * k2] * lo2f(u0) + hsm[2 * k2 + 1] * hi2f(u0);
            a1 += hsm[2 * k2 + 2] * lo2f(u1) + hsm[2 * k2 + 3] * hi2f(u1);
        }
        x2s[t] = a0 + a1;
    }
    __syncthreads();

    if (t < 128) {
        const int d = t;
        float vw = muV[d] * muW[d] + muV[128 + d] * muW[128 + d] + muV[256 + d] * muW[256 + d];
        if (i < 192)
            q_out[((long)b * 192 + i) * 128 + d] = qv + x2s[d] + x2s[256 + d] * vw;
        #pragma unroll
        for (int r = 0; r < 3; ++r)
            mu_out[((long)bi * 3 + r) * 128 + d] =
                mu_s[r * 128 + d] + x2s[128 + d] * muW[r * 128 + d];
    }
}

extern "C" void kernel_launch(void* const* d_in, const int* in_sizes, int n_in,
                              void* d_out, int out_size, void* d_ws, size_t ws_size,
                              hipStream_t stream) {
    (void)in_sizes; (void)n_in; (void)out_size;
    const float* s_heavy  = (const float*)d_in[0];
    const float* v_all    = (const float*)d_in[1];
    const float* rbf      = (const float*)d_in[2];
    const float* dir_ij   = (const float*)d_in[3];
    const float* mask_ij  = (const float*)d_in[4];
    const int*   is_h     = (const int*)d_in[5];
    const float* h_emb    = (const float*)d_in[6];
    const float* W_filter = (const float*)d_in[7];
    const float* b_filter = (const float*)d_in[8];
    const float* norm1_w  = (const float*)d_in[9];
    const float* W_i1     = (const float*)d_in[10];
    const float* b_i1     = (const float*)d_in[11];
    const float* W_i2     = (const float*)d_in[12];
    const float* b_i2     = (const float*)d_in[13];
    const float* norm2_w  = (const float*)d_in[14];
    const float* W_m1     = (const float*)d_in[15];
    const float* b_m1     = (const float*)d_in[16];
    const float* W_m2     = (const float*)d_in[17];
    const float* b_m2     = (const float*)d_in[18];
    const float* W_mu     = (const float*)d_in[19];

    // ws layout (f32 units): s_all 0 | x 65536 | Bg 262144(+163840) | Wmu_p 425984(+16384)
    //  | Wm1_p 442368(+32768) | Wm2_p 475136(+24576) | Wfb_p 499712(+4032)
    const size_t need = (size_t)503744 * 4;
    if (ws_size < need) return;
    float* ws    = (float*)d_ws;
    float* s_all = ws;
    float* x     = ws + 65536;
    unsigned* Bg    = (unsigned*)(ws + 262144);
    unsigned* Wmu_p = (unsigned*)(ws + 425984);
    unsigned* Wm1_p = (unsigned*)(ws + 442368);
    unsigned* Wm2_p = (unsigned*)(ws + 475136);
    unsigned* Wfb_p = (unsigned*)(ws + 499712);

    float* q_out  = (float*)d_out;               // (2,192,128)
    float* mu_out = q_out + 2 * 192 * 128;       // (2,256,3,128)

    kA<<<576, 256, 0, stream>>>(s_heavy, is_h, h_emb, norm1_w, W_i1, b_i1, W_i2, b_i2,
                                W_mu, W_m1, W_m2, W_filter, b_filter,
                                s_all, x, Wmu_p, Wm1_p, Wm2_p, Wfb_p);
    kX2<<<64, 640, 0, stream>>>(x, v_all, Bg);
    kBC<<<512, 512, 0, stream>>>(rbf, dir_ij, mask_ij, v_all, s_all, Bg,
                                 Wmu_p, norm2_w, Wm1_p, b_m1, Wm2_p, b_m2, Wfb_p,
                                 q_out, mu_out);
}

// Round 15
// 48.833 us; speedup vs baseline: 1.4539x; 1.0343x over previous
//
#include <hip/hip_runtime.h>
#include <hip/hip_bf16.h>

#define DEV static __device__ __forceinline__

typedef __attribute__((ext_vector_type(8))) short bf16x8;
typedef __attribute__((ext_vector_type(4))) float f32x4;

DEV float sigm(float x) { return 1.0f / (1.0f + __expf(-x)); }

DEV unsigned pack2bf(float a, float b) {
    unsigned r;
    asm("v_cvt_pk_bf16_f32 %0, %1, %2" : "=v"(r) : "v"(a), "v"(b));
    return r;
}
DEV unsigned short f2bf(float a) {
    unsigned ua = __float_as_uint(a);
    return (unsigned short)((ua + 0x7FFF + ((ua >> 16) & 1)) >> 16);
}
DEV float bfu2f(unsigned short u) { return __uint_as_float(((unsigned)u) << 16); }
DEV float lo2f(unsigned u) { return __uint_as_float(u << 16); }
DEV float hi2f(unsigned u) { return __uint_as_float(u & 0xffff0000u); }

// B=2, N=256, Nh=192, D=128, R=20

// Kernel A: blocks <512: per-atom s_all + x. blocks 512..575: pack mixing weights to bf16.
__global__ __launch_bounds__(256) void kA(
    const float* __restrict__ s_heavy, const int* __restrict__ is_h,
    const float* __restrict__ h_emb, const float* __restrict__ norm1_w,
    const float* __restrict__ W_i1, const float* __restrict__ b_i1,
    const float* __restrict__ W_i2, const float* __restrict__ b_i2,
    const float* __restrict__ W_mu, const float* __restrict__ W_m1,
    const float* __restrict__ W_m2, const float* __restrict__ W_filter,
    const float* __restrict__ b_filter,
    float* __restrict__ s_all, float* __restrict__ x,
    unsigned* __restrict__ Wmu_p, unsigned* __restrict__ Wm1_p,
    unsigned* __restrict__ Wm2_p, unsigned* __restrict__ Wfb_p)
{
    const int blk = blockIdx.x;
    const int t = threadIdx.x;
    if (blk >= 512) {
        const int idx0 = (blk - 512) * 256 + t;       // 0..16383
        {   // W_mu pairs: 64 k2 x 256 c
            int k2 = idx0 >> 8, c = idx0 & 255;
            Wmu_p[idx0] = pack2bf(W_mu[(2 * k2) * 256 + c], W_mu[(2 * k2 + 1) * 256 + c]);
        }
        #pragma unroll
        for (int r = 0; r < 2; ++r) {                 // W_m1 pairs: 128 k2 x 256 c
            int s = idx0 + r * 16384;
            int k2 = s >> 8, c = s & 255;
            Wm1_p[s] = pack2bf(W_m1[(2 * k2) * 256 + c], W_m1[(2 * k2 + 1) * 256 + c]);
        }
        for (int s = idx0; s < 24576; s += 16384) {   // W_m2 pairs: 64 k2 x 384 c
            int k2 = s / 384, c = s - k2 * 384;
            Wm2_p[s] = pack2bf(W_m2[(2 * k2) * 384 + c], W_m2[(2 * k2 + 1) * 384 + c]);
        }
        for (int s = idx0; s < 4032; s += 16384) {    // [W_filter(7680) | b_filter(384)] u16
            int e = 2 * s;
            float v0 = (e < 7680) ? W_filter[e] : b_filter[e - 7680];
            float v1 = (e + 1 < 7680) ? W_filter[e + 1] : b_filter[e + 1 - 7680];
            Wfb_p[s] = pack2bf(v0, v1);
        }
        return;
    }
    const int bi = blk;
    const int b = bi >> 8, i = bi & 255;
    __shared__ float y[128];
    __shared__ float o[256];
    __shared__ float h[128];
    __shared__ float red[4];

    float s = 0.f;
    if (t < 128) {
        if (is_h[bi] != 0) s = h_emb[t];
        else if (i < 192) s = s_heavy[(b * 192 + i) * 128 + t];
        s_all[bi * 128 + t] = s;
    }
    float ss = s * s;
    #pragma unroll
    for (int off = 32; off > 0; off >>= 1) ss += __shfl_xor(ss, off, 64);
    if ((t & 63) == 0) red[t >> 6] = ss;
    __syncthreads();
    float v = (red[0] + red[1] + red[2] + red[3]) * (1.0f / 128.0f);
    float inv = rsqrtf(v + 1e-6f);
    if (t < 128) y[t] = s * inv * (1.0f + norm1_w[t]);
    __syncthreads();

    float acc = b_i1[t];
    #pragma unroll 8
    for (int k = 0; k < 128; ++k) acc += y[k] * W_i1[k * 256 + t];
    o[t] = acc;
    __syncthreads();
    if (t < 128) {
        float a = o[t], g = o[t + 128];
        h[t] = a * sigm(a) * sigm(g);
    }
    __syncthreads();
    for (int c = t; c < 384; c += 256) {
        float a2 = b_i2[c];
        #pragma unroll 8
        for (int k = 0; k < 128; ++k) a2 += h[k] * W_i2[k * 384 + c];
        x[(long)bi * 384 + c] = a2;
    }
}

// Kernel X2: build frag-contiguous B panel (uint4 per (b,kt,g,col) = 8 bf16 along j).
__global__ __launch_bounds__(640) void kX2(
    const float* __restrict__ x, const float* __restrict__ v_all,
    unsigned* __restrict__ Bg)
{
    int blk = blockIdx.x;
    const int g = blk & 3; blk >>= 2;
    const int kt = blk & 7; const int b = blk >> 3;
    const int col = threadIdx.x;
    const int j0 = kt * 32 + g * 8;
    const float* xb = x + (long)b * 98304;
    const float* vb = v_all + (long)b * 98304;

    float vals[8];
    if (col < 256) {
        #pragma unroll
        for (int jj = 0; jj < 8; ++jj) vals[jj] = xb[(j0 + jj) * 384 + col];
    } else {
        const int cg = col - 256, r3 = cg >> 7, c3 = cg & 127;
        #pragma unroll
        for (int jj = 0; jj < 8; ++jj) {
            const int j = j0 + jj;
            vals[jj] = vb[j * 384 + r3 * 128 + c3] * xb[j * 384 + 256 + c3];
        }
    }
    uint4 outv = make_uint4(pack2bf(vals[0], vals[1]), pack2bf(vals[2], vals[3]),
                            pack2bf(vals[4], vals[5]), pack2bf(vals[6], vals[7]));
    *(uint4*)&Bg[(((long)(b * 8 + kt) * 4 + g) * 640 + col) * 4] = outv;
}

// Kernel BC (fused B+C), 53248 B LDS; (512,4) -> VGPR<=64 target, 3 blocks/CU via LDS.
__global__ __launch_bounds__(512, 4) void kBC(
    const float* __restrict__ rbf, const float* __restrict__ dir_ij,
    const float* __restrict__ mask_ij, const float* __restrict__ v_all,
    const float* __restrict__ s_all, const unsigned* __restrict__ Bg,
    const unsigned* __restrict__ Wmu_p, const float* __restrict__ norm2_w,
    const unsigned* __restrict__ Wm1_p, const float* __restrict__ b_m1,
    const unsigned* __restrict__ Wm2_p, const float* __restrict__ b_m2,
    const unsigned* __restrict__ Wfb_p,
    float* __restrict__ q_out, float* __restrict__ mu_out)
{
    const int bi = blockIdx.x, b = bi >> 8, i = bi & 255;
    const int t = threadIdx.x;
    const int lane = t & 63, w = t >> 6, g = lane >> 4, l16 = lane & 15;

    __shared__ __align__(16) unsigned short A16[96 * 264];  // 50688 B
    __shared__ unsigned short dir16[768];                   // 1536 B
    __shared__ float m_s[256];                              // 1024 B

    // ---- pass 1: stage m, dir16 (bf16); zero pad rows 21-31, 95 ----
    if (t < 256) m_s[t] = mask_ij[(long)bi * 256 + t];
    for (int idx = t; idx < 768; idx += 512) dir16[idx] = f2bf(dir_ij[(long)bi * 768 + idx]);
    {
        unsigned* Az = (unsigned*)A16;
        for (int s2 = t; s2 < 1452; s2 += 512) Az[2772 + s2] = 0;   // rows 21-31
        if (t < 132) Az[12540 + t] = 0;                              // row 95
    }
    __syncthreads();

    // ---- pass 2: even-j paired rbf load + A build (u32 writes, cvt_pk) ----
    {
        unsigned* A32 = (unsigned*)A16;
        #pragma unroll
        for (int it = 0; it < 5; ++it) {
            const int idx = it * 512 + t;            // 0..2559
            const int j2 = idx / 20, r = idx - j2 * 20;
            const int j = 2 * j2;
            const float v0 = rbf[(long)bi * 5120 + j2 * 40 + r];
            const float v1 = rbf[(long)bi * 5120 + j2 * 40 + 20 + r];
            const float vm0 = v0 * m_s[j], vm1 = v1 * m_s[j + 1];
            const float d00 = bfu2f(dir16[j * 3 + 0]), d01 = bfu2f(dir16[j * 3 + 3]);
            const float d10 = bfu2f(dir16[j * 3 + 1]), d11 = bfu2f(dir16[j * 3 + 4]);
            const float d20 = bfu2f(dir16[j * 3 + 2]), d21 = bfu2f(dir16[j * 3 + 5]);
            A32[r * 132 + j2]        = pack2bf(vm0, vm1);
            A32[(32 + r) * 132 + j2] = pack2bf(vm0 * d00, vm1 * d01);
            A32[(53 + r) * 132 + j2] = pack2bf(vm0 * d10, vm1 * d11);
            A32[(74 + r) * 132 + j2] = pack2bf(vm0 * d20, vm1 * d21);
        }
        if (t < 128) {   // mask rows: 20, 52, 73, 94 (j-pairs)
            const int j2 = t, j = 2 * t;
            const float m0 = m_s[j], m1 = m_s[j + 1];
            const float d00 = bfu2f(dir16[j * 3 + 0]), d01 = bfu2f(dir16[j * 3 + 3]);
            const float d10 = bfu2f(dir16[j * 3 + 1]), d11 = bfu2f(dir16[j * 3 + 4]);
            const float d20 = bfu2f(dir16[j * 3 + 2]), d21 = bfu2f(dir16[j * 3 + 5]);
            A32[20 * 132 + j2] = pack2bf(m0, m1);
            A32[52 * 132 + j2] = pack2bf(m0 * d00, m1 * d01);
            A32[73 * 132 + j2] = pack2bf(m0 * d10, m1 * d11);
            A32[94 * 132 + j2] = pack2bf(m0 * d20, m1 * d21);
        }
    }
    __syncthreads();

    // ---- tile assignment ----
    int colR[4];
    #pragma unroll
    for (int ci = 0; ci < 4; ++ci) {
        int ct = (w < 2) ? (4 * w + ci) : (4 * w + 8 + ci);
        colR[ci] = ct * 16 + l16;
    }
    const int col2 = (8 + w) * 16 + l16;

    const unsigned* BgB = Bg + (long)b * 81920;
    const unsigned short* Wfb16 = (const unsigned short*)Wfb_p;

    f32x4 accR[4][2];
    f32x4 acc2[4];
    #pragma unroll
    for (int ci = 0; ci < 4; ++ci) {
        #pragma unroll
        for (int rt = 0; rt < 2; ++rt) accR[ci][rt] = {0.f, 0.f, 0.f, 0.f};
        acc2[ci] = {0.f, 0.f, 0.f, 0.f};
    }

    // ---- GEMM: K = 256 j = 8 k-steps of 32 ----
    #pragma unroll 2
    for (int kt = 0; kt < 8; ++kt) {
        bf16x8 af[6];
        #pragma unroll
        for (int rt = 0; rt < 6; ++rt)
            af[rt] = *(const bf16x8*)&A16[(rt * 16 + l16) * 264 + kt * 32 + g * 8];
        const unsigned* Bk = BgB + ((long)kt * 4 + g) * 640 * 4;
        bf16x8 bfr[5];
        #pragma unroll
        for (int u = 0; u < 4; ++u)
            bfr[u] = *(const bf16x8*)&Bk[colR[u] * 4];
        bfr[4] = *(const bf16x8*)&Bk[col2 * 4];
        #pragma unroll
        for (int ci = 0; ci < 4; ++ci) {
            accR[ci][0] = __builtin_amdgcn_mfma_f32_16x16x32_bf16(af[0], bfr[ci], accR[ci][0], 0, 0, 0);
            accR[ci][1] = __builtin_amdgcn_mfma_f32_16x16x32_bf16(af[1], bfr[ci], accR[ci][1], 0, 0, 0);
        }
        #pragma unroll
        for (int rt = 0; rt < 4; ++rt)
            acc2[rt] = __builtin_amdgcn_mfma_f32_16x16x32_bf16(af[2 + rt], bfr[4], acc2[rt], 0, 0, 0);
    }

    // ---- pre-barrier: all epilogue contractions in registers ----
    float p3[3] = {0.f, 0.f, 0.f};
    {
        const int c = 128 + 16 * w + l16;
        #pragma unroll
        for (int rt = 0; rt < 4; ++rt) {
            #pragma unroll
            for (int e = 0; e < 4; ++e) {
                int l = rt * 16 + g * 4 + e;
                if (l < 63) {
                    int r3 = (l >= 42) ? 2 : ((l >= 21) ? 1 : 0);
                    int rr = l - 21 * r3;
                    float wgt = bfu2f((rr < 20) ? Wfb16[rr * 384 + c] : Wfb16[7680 + c]);
                    p3[r3] += wgt * acc2[rt][e];
                }
            }
        }
        #pragma unroll
        for (int r3 = 0; r3 < 3; ++r3) {
            p3[r3] += __shfl_xor(p3[r3], 16, 64);
            p3[r3] += __shfl_xor(p3[r3], 32, 64);
        }
    }
    float pq[4];
    #pragma unroll
    for (int ci = 0; ci < 4; ++ci) {
        const int cwf = (w < 2) ? colR[ci] : (256 + ((colR[ci] - 256) & 127));
        float p = 0.f;
        #pragma unroll
        for (int rt = 0; rt < 2; ++rt) {
            #pragma unroll
            for (int e = 0; e < 4; ++e) {
                int row = rt * 16 + g * 4 + e;
                if (row <= 20) {
                    float wgt = bfu2f((row < 20) ? Wfb16[row * 384 + cwf] : Wfb16[7680 + cwf]);
                    p += wgt * accR[ci][rt][e];
                }
            }
        }
        p += __shfl_xor(p, 16, 64);
        p += __shfl_xor(p, 32, 64);
        pq[ci] = p;
    }
    const float vpre = (t < 384) ? v_all[(long)bi * 384 + t] : 0.f;
    __syncthreads();   // A16 dead from here; aliased writes below are safe

    // ---- aliased LDS buffers on A16 (12672 f32 available) ----
    float* fb      = (float*)A16;
    float* dmuR_s  = fb;           // 384
    float* dmumu_s = fb + 384;     // 384
    float* q_s     = fb + 768;     // 128
    float* mu_s    = fb + 896;     // 384
    float* part    = fb + 1280;    // [2][768]
    float* muV     = fb + 2816;    // 384
    float* muW     = fb + 3200;    // 384
    float* ctx     = fb + 3584;    // 256
    float* o_part  = fb + 3840;    // [2][256]
    float* hsm     = fb + 4352;    // 128
    float* x2s     = fb + 4480;    // 384
    float* red     = fb + 4864;    // 8

    if (lane < 16) {
        #pragma unroll
        for (int r3 = 0; r3 < 3; ++r3) dmuR_s[r3 * 128 + 16 * w + l16] = p3[r3];
        #pragma unroll
        for (int ci = 0; ci < 4; ++ci) {
            if (w < 2) {
                q_s[colR[ci]] = s_all[bi * 128 + colR[ci]] + pq[ci];
            } else {
                dmumu_s[colR[ci] - 256] = pq[ci];
            }
        }
    }
    __syncthreads();
    if (t < 384) mu_s[t] = vpre + dmuR_s[t] + dmumu_s[t];
    __syncthreads();

    // ================= Phase C: mixing =================
    const int c = t & 255, kh = t >> 8;
    float qv = (t < 128) ? q_s[t] : 0.f;

    // mu_mix (split-K halves, packed pairs along k)
    {
        float m0 = 0.f, m1 = 0.f, m2 = 0.f;
        const int k20 = kh * 32;
        #pragma unroll 8
        for (int k2 = k20; k2 < k20 + 32; ++k2) {
            unsigned u = Wmu_p[k2 * 256 + c];
            float w0 = lo2f(u), w1 = hi2f(u);
            m0 += mu_s[2 * k2] * w0 + mu_s[2 * k2 + 1] * w1;
            m1 += mu_s[128 + 2 * k2] * w0 + mu_s[128 + 2 * k2 + 1] * w1;
            m2 += mu_s[256 + 2 * k2] * w0 + mu_s[256 + 2 * k2 + 1] * w1;
        }
        part[kh * 768 + c] = m0; part[kh * 768 + 256 + c] = m1; part[kh * 768 + 512 + c] = m2;
    }
    float ss = qv * qv;
    #pragma unroll
    for (int off = 32; off > 0; off >>= 1) ss += __shfl_xor(ss, off, 64);
    if ((t & 63) == 0) red[t >> 6] = ss;
    __syncthreads();
    for (int idx = t; idx < 768; idx += 512) {
        const int r3 = idx >> 8, cc = idx & 255;
        float val = part[idx] + part[768 + idx];
        if (cc < 128) muV[r3 * 128 + cc] = val;
        else          muW[r3 * 128 + (cc - 128)] = val;
    }
    __syncthreads();
    float mean = (red[0] + red[1] + red[2] + red[3] + red[4] + red[5] + red[6] + red[7])
                 * (1.0f / 128.0f);
    if (t < 128) {
        ctx[t] = qv * rsqrtf(mean + 1e-6f) * (1.0f + norm2_w[t]);
    } else if (t < 256) {
        int d2 = t - 128;
        ctx[t] = sqrtf(muV[d2] * muV[d2] + muV[128 + d2] * muV[128 + d2]
                       + muV[256 + d2] * muV[256 + d2] + 1e-6f);
    }
    __syncthreads();

    // o = ctx @ W_m1 (split-K halves, packed, dual accumulators)
    {
        float acc0 = 0.f, acc1 = 0.f;
        const int k20 = kh * 64;
        #pragma unroll 8
        for (int k2 = k20; k2 < k20 + 64; k2 += 2) {
            unsigned u0 = Wm1_p[k2 * 256 + c];
            unsigned u1 = Wm1_p[(k2 + 1) * 256 + c];
            acc0 += ctx[2 * k2] * lo2f(u0) + ctx[2 * k2 + 1] * hi2f(u0);
            acc1 += ctx[2 * k2 + 2] * lo2f(u1) + ctx[2 * k2 + 3] * hi2f(u1);
        }
        o_part[kh * 256 + c] = acc0 + acc1;
    }
    __syncthreads();
    if (t < 128) {
        float a  = o_part[t]       + o_part[256 + t]       + b_m1[t];
        float gg = o_part[t + 128] + o_part[256 + t + 128] + b_m1[t + 128];
        hsm[t] = a * sigm(a) * sigm(gg);
    }
    __syncthreads();
    if (t < 384) {
        float a0 = b_m2[t], a1 = 0.f;
        #pragma unroll 8
        for (int k2 = 0; k2 < 64; k2 += 2) {
            unsigned u0 = Wm2_p[k2 * 384 + t];
            unsigned u1 = Wm2_p[(k2 + 1) * 384 + t];
            a0 += hsm[2 * k2] * lo2f(u0) + hsm[2 * k2 + 1] * hi2f(u0);
            a1 += hsm[2 * k2 + 2] * lo2f(u1) + hsm[2 * k2 + 3] * hi2f(u1);
        }
        x2s[t] = a0 + a1;
    }
    __syncthreads();

    if (t < 128) {
        const int d = t;
        float vw = muV[d] * muW[d] + muV[128 + d] * muW[128 + d] + muV[256 + d] * muW[256 + d];
        if (i < 192)
            q_out[((long)b * 192 + i) * 128 + d] = qv + x2s[d] + x2s[256 + d] * vw;
        #pragma unroll
        for (int r = 0; r < 3; ++r)
            mu_out[((long)bi * 3 + r) * 128 + d] =
                mu_s[r * 128 + d] + x2s[128 + d] * muW[r * 128 + d];
    }
}

extern "C" void kernel_launch(void* const* d_in, const int* in_sizes, int n_in,
                              void* d_out, int out_size, void* d_ws, size_t ws_size,
                              hipStream_t stream) {
    (void)in_sizes; (void)n_in; (void)out_size;
    const float* s_heavy  = (const float*)d_in[0];
    const float* v_all    = (const float*)d_in[1];
    const float* rbf      = (const float*)d_in[2];
    const float* dir_ij   = (const float*)d_in[3];
    const float* mask_ij  = (const float*)d_in[4];
    const int*   is_h     = (const int*)d_in[5];
    const float* h_emb    = (const float*)d_in[6];
    const float* W_filter = (const float*)d_in[7];
    const float* b_filter = (const float*)d_in[8];
    const float* norm1_w  = (const float*)d_in[9];
    const float* W_i1     = (const float*)d_in[10];
    const float* b_i1     = (const float*)d_in[11];
    const float* W_i2     = (const float*)d_in[12];
    const float* b_i2     = (const float*)d_in[13];
    const float* norm2_w  = (const float*)d_in[14];
    const float* W_m1     = (const float*)d_in[15];
    const float* b_m1     = (const float*)d_in[16];
    const float* W_m2     = (const float*)d_in[17];
    const float* b_m2     = (const float*)d_in[18];
    const float* W_mu     = (const float*)d_in[19];

    // ws layout (f32 units): s_all 0 | x 65536 | Bg 262144(+163840) | Wmu_p 425984(+16384)
    //  | Wm1_p 442368(+32768) | Wm2_p 475136(+24576) | Wfb_p 499712(+4032)
    const size_t need = (size_t)503744 * 4;
    if (ws_size < need) return;
    float* ws    = (float*)d_ws;
    float* s_all = ws;
    float* x     = ws + 65536;
    unsigned* Bg    = (unsigned*)(ws + 262144);
    unsigned* Wmu_p = (unsigned*)(ws + 425984);
    unsigned* Wm1_p = (unsigned*)(ws + 442368);
    unsigned* Wm2_p = (unsigned*)(ws + 475136);
    unsigned* Wfb_p = (unsigned*)(ws + 499712);

    float* q_out  = (float*)d_out;               // (2,192,128)
    float* mu_out = q_out + 2 * 192 * 128;       // (2,256,3,128)

    kA<<<576, 256, 0, stream>>>(s_heavy, is_h, h_emb, norm1_w, W_i1, b_i1, W_i2, b_i2,
                                W_mu, W_m1, W_m2, W_filter, b_filter,
                                s_all, x, Wmu_p, Wm1_p, Wm2_p, Wfb_p);
    kX2<<<64, 640, 0, stream>>>(x, v_all, Bg);
    kBC<<<512, 512, 0, stream>>>(rbf, dir_ij, mask_ij, v_all, s_all, Bg,
                                 Wmu_p, norm2_w, Wm1_p, b_m1, Wm2_p, b_m2, Wfb_p,
                                 q_out, mu_out);
}

// Round 17
// 46.709 us; speedup vs baseline: 1.5200x; 1.0455x over previous
//
#include <hip/hip_runtime.h>
#include <hip/hip_bf16.h>

#define DEV static __device__ __forceinline__

typedef __attribute__((ext_vector_type(8))) short bf16x8;
typedef __attribute__((ext_vector_type(4))) float f32x4;

DEV float sigm(float x) { return 1.0f / (1.0f + __expf(-x)); }

DEV unsigned pack2bf(float a, float b) {
    unsigned r;
    asm("v_cvt_pk_bf16_f32 %0, %1, %2" : "=v"(r) : "v"(a), "v"(b));
    return r;
}
DEV unsigned short f2bf(float a) {
    unsigned ua = __float_as_uint(a);
    return (unsigned short)((ua + 0x7FFF + ((ua >> 16) & 1)) >> 16);
}
DEV float bfu2f(unsigned short u) { return __uint_as_float(((unsigned)u) << 16); }
DEV float lo2f(unsigned u) { return __uint_as_float(u << 16); }
DEV float hi2f(unsigned u) { return __uint_as_float(u & 0xffff0000u); }

// B=2, N=256, Nh=192, D=128, R=20
// Packed mixing-weight layout: W_q[(k2>>1)*2C + c*2 + (k2&1)], each u32 = bf16 pair (2k2, 2k2+1).
// Phase-C threads read uint2 -> 4 consecutive k weights, 8B/lane fully coalesced.

// Kernel A: blocks <512: per-atom s_all + x. blocks 512..575: pack mixing weights to bf16.
__global__ __launch_bounds__(256) void kA(
    const float* __restrict__ s_heavy, const int* __restrict__ is_h,
    const float* __restrict__ h_emb, const float* __restrict__ norm1_w,
    const float* __restrict__ W_i1, const float* __restrict__ b_i1,
    const float* __restrict__ W_i2, const float* __restrict__ b_i2,
    const float* __restrict__ W_mu, const float* __restrict__ W_m1,
    const float* __restrict__ W_m2, const float* __restrict__ W_filter,
    const float* __restrict__ b_filter,
    float* __restrict__ s_all, float* __restrict__ x,
    unsigned* __restrict__ Wmu_p, unsigned* __restrict__ Wm1_p,
    unsigned* __restrict__ Wm2_p, unsigned* __restrict__ Wfb_p)
{
    const int blk = blockIdx.x;
    const int t = threadIdx.x;
    if (blk >= 512) {
        const int idx0 = (blk - 512) * 256 + t;       // 0..16383
        {   // W_mu: k2 in [0,64), c in [0,256)
            int k2 = idx0 >> 8, c = idx0 & 255;
            Wmu_p[(k2 >> 1) * 512 + c * 2 + (k2 & 1)] =
                pack2bf(W_mu[(2 * k2) * 256 + c], W_mu[(2 * k2 + 1) * 256 + c]);
        }
        #pragma unroll
        for (int r = 0; r < 2; ++r) {                 // W_m1: k2 in [0,128)
            int s = idx0 + r * 16384;
            int k2 = s >> 8, c = s & 255;
            Wm1_p[(k2 >> 1) * 512 + c * 2 + (k2 & 1)] =
                pack2bf(W_m1[(2 * k2) * 256 + c], W_m1[(2 * k2 + 1) * 256 + c]);
        }
        for (int s = idx0; s < 24576; s += 16384) {   // W_m2: k2 in [0,64), c in [0,384)
            int k2 = s / 384, c = s - k2 * 384;
            Wm2_p[(k2 >> 1) * 768 + c * 2 + (k2 & 1)] =
                pack2bf(W_m2[(2 * k2) * 384 + c], W_m2[(2 * k2 + 1) * 384 + c]);
        }
        for (int s = idx0; s < 4032; s += 16384) {    // [W_filter(7680) | b_filter(384)] u16
            int e = 2 * s;
            float v0 = (e < 7680) ? W_filter[e] : b_filter[e - 7680];
            float v1 = (e + 1 < 7680) ? W_filter[e + 1] : b_filter[e + 1 - 7680];
            Wfb_p[s] = pack2bf(v0, v1);
        }
        return;
    }
    const int bi = blk;
    const int b = bi >> 8, i = bi & 255;
    __shared__ float y[128];
    __shared__ float o[256];
    __shared__ float h[128];
    __shared__ float red[4];

    float s = 0.f;
    if (t < 128) {
        if (is_h[bi] != 0) s = h_emb[t];
        else if (i < 192) s = s_heavy[(b * 192 + i) * 128 + t];
        s_all[bi * 128 + t] = s;
    }
    float ss = s * s;
    #pragma unroll
    for (int off = 32; off > 0; off >>= 1) ss += __shfl_xor(ss, off, 64);
    if ((t & 63) == 0) red[t >> 6] = ss;
    __syncthreads();
    float v = (red[0] + red[1] + red[2] + red[3]) * (1.0f / 128.0f);
    float inv = rsqrtf(v + 1e-6f);
    if (t < 128) y[t] = s * inv * (1.0f + norm1_w[t]);
    __syncthreads();

    {
        float acc0 = 0.f, acc1 = 0.f;
        #pragma unroll 8
        for (int k = 0; k < 128; k += 2) {
            acc0 += y[k] * W_i1[k * 256 + t];
            acc1 += y[k + 1] * W_i1[(k + 1) * 256 + t];
        }
        o[t] = acc0 + acc1 + b_i1[t];
    }
    __syncthreads();
    if (t < 128) {
        float a = o[t], g = o[t + 128];
        h[t] = a * sigm(a) * sigm(g);
    }
    __syncthreads();
    for (int c = t; c < 384; c += 256) {
        float a0 = b_i2[c], a1 = 0.f;
        #pragma unroll 8
        for (int k = 0; k < 128; k += 2) {
            a0 += h[k] * W_i2[k * 384 + c];
            a1 += h[k + 1] * W_i2[(k + 1) * 384 + c];
        }
        x[(long)bi * 384 + c] = a0 + a1;
    }
}

// Kernel X2: build frag-contiguous B panel (uint4 per (b,kt,g,col) = 8 bf16 along j).
__global__ __launch_bounds__(640) void kX2(
    const float* __restrict__ x, const float* __restrict__ v_all,
    unsigned* __restrict__ Bg)
{
    int blk = blockIdx.x;
    const int g = blk & 3; blk >>= 2;
    const int kt = blk & 7; const int b = blk >> 3;
    const int col = threadIdx.x;
    const int j0 = kt * 32 + g * 8;
    const float* xb = x + (long)b * 98304;
    const float* vb = v_all + (long)b * 98304;

    float vals[8];
    if (col < 256) {
        #pragma unroll
        for (int jj = 0; jj < 8; ++jj) vals[jj] = xb[(j0 + jj) * 384 + col];
    } else {
        const int cg = col - 256, r3 = cg >> 7, c3 = cg & 127;
        #pragma unroll
        for (int jj = 0; jj < 8; ++jj) {
            const int j = j0 + jj;
            vals[jj] = vb[j * 384 + r3 * 128 + c3] * xb[j * 384 + 256 + c3];
        }
    }
    uint4 outv = make_uint4(pack2bf(vals[0], vals[1]), pack2bf(vals[2], vals[3]),
                            pack2bf(vals[4], vals[5]), pack2bf(vals[6], vals[7]));
    *(uint4*)&Bg[(((long)(b * 8 + kt) * 4 + g) * 640 + col) * 4] = outv;
}

// Kernel BC (fused B+C), 53248 B LDS; (512,4) -> VGPR<=64, 3 blocks/CU via LDS.
__global__ __launch_bounds__(512, 4) void kBC(
    const float* __restrict__ rbf, const float* __restrict__ dir_ij,
    const float* __restrict__ mask_ij, const float* __restrict__ v_all,
    const float* __restrict__ s_all, const unsigned* __restrict__ Bg,
    const unsigned* __restrict__ Wmu_p, const float* __restrict__ norm2_w,
    const unsigned* __restrict__ Wm1_p, const float* __restrict__ b_m1,
    const unsigned* __restrict__ Wm2_p, const float* __restrict__ b_m2,
    const unsigned* __restrict__ Wfb_p,
    float* __restrict__ q_out, float* __restrict__ mu_out)
{
    const int bi = blockIdx.x, b = bi >> 8, i = bi & 255;
    const int t = threadIdx.x;
    const int lane = t & 63, w = t >> 6, g = lane >> 4, l16 = lane & 15;

    __shared__ __align__(16) unsigned short A16[96 * 264];  // 50688 B
    __shared__ unsigned short dir16[768];                   // 1536 B
    __shared__ float m_s[256];                              // 1024 B

    // ---- pass 1: stage m, dir16 (bf16); zero pad rows 21-31, 95 ----
    if (t < 256) m_s[t] = mask_ij[(long)bi * 256 + t];
    for (int idx = t; idx < 768; idx += 512) dir16[idx] = f2bf(dir_ij[(long)bi * 768 + idx]);
    {
        unsigned* Az = (unsigned*)A16;
        for (int s2 = t; s2 < 1452; s2 += 512) Az[2772 + s2] = 0;   // rows 21-31
        if (t < 132) Az[12540 + t] = 0;                              // row 95
    }
    __syncthreads();

    // ---- pass 2: even-j paired rbf load + A build (u32 writes, cvt_pk) ----
    {
        unsigned* A32 = (unsigned*)A16;
        #pragma unroll
        for (int it = 0; it < 5; ++it) {
            const int idx = it * 512 + t;            // 0..2559
            const int j2 = idx / 20, r = idx - j2 * 20;
            const int j = 2 * j2;
            const float v0 = rbf[(long)bi * 5120 + j2 * 40 + r];
            const float v1 = rbf[(long)bi * 5120 + j2 * 40 + 20 + r];
            const float vm0 = v0 * m_s[j], vm1 = v1 * m_s[j + 1];
            const float d00 = bfu2f(dir16[j * 3 + 0]), d01 = bfu2f(dir16[j * 3 + 3]);
            const float d10 = bfu2f(dir16[j * 3 + 1]), d11 = bfu2f(dir16[j * 3 + 4]);
            const float d20 = bfu2f(dir16[j * 3 + 2]), d21 = bfu2f(dir16[j * 3 + 5]);
            A32[r * 132 + j2]        = pack2bf(vm0, vm1);
            A32[(32 + r) * 132 + j2] = pack2bf(vm0 * d00, vm1 * d01);
            A32[(53 + r) * 132 + j2] = pack2bf(vm0 * d10, vm1 * d11);
            A32[(74 + r) * 132 + j2] = pack2bf(vm0 * d20, vm1 * d21);
        }
        if (t < 128) {   // mask rows: 20, 52, 73, 94 (j-pairs)
            const int j2 = t, j = 2 * t;
            const float m0 = m_s[j], m1 = m_s[j + 1];
            const float d00 = bfu2f(dir16[j * 3 + 0]), d01 = bfu2f(dir16[j * 3 + 3]);
            const float d10 = bfu2f(dir16[j * 3 + 1]), d11 = bfu2f(dir16[j * 3 + 4]);
            const float d20 = bfu2f(dir16[j * 3 + 2]), d21 = bfu2f(dir16[j * 3 + 5]);
            A32[20 * 132 + j2] = pack2bf(m0, m1);
            A32[52 * 132 + j2] = pack2bf(m0 * d00, m1 * d01);
            A32[73 * 132 + j2] = pack2bf(m0 * d10, m1 * d11);
            A32[94 * 132 + j2] = pack2bf(m0 * d20, m1 * d21);
        }
    }
    __syncthreads();

    // ---- tile assignment ----
    int colR[4];
    #pragma unroll
    for (int ci = 0; ci < 4; ++ci) {
        int ct = (w < 2) ? (4 * w + ci) : (4 * w + 8 + ci);
        colR[ci] = ct * 16 + l16;
    }
    const int col2 = (8 + w) * 16 + l16;

    const unsigned* BgB = Bg + (long)b * 81920;
    const unsigned short* Wfb16 = (const unsigned short*)Wfb_p;

    f32x4 accR[4][2];
    f32x4 acc2[4];
    #pragma unroll
    for (int ci = 0; ci < 4; ++ci) {
        #pragma unroll
        for (int rt = 0; rt < 2; ++rt) accR[ci][rt] = {0.f, 0.f, 0.f, 0.f};
        acc2[ci] = {0.f, 0.f, 0.f, 0.f};
    }

    // ---- GEMM: K = 256 j = 8 k-steps of 32 ----
    #pragma unroll 2
    for (int kt = 0; kt < 8; ++kt) {
        bf16x8 af[6];
        #pragma unroll
        for (int rt = 0; rt < 6; ++rt)
            af[rt] = *(const bf16x8*)&A16[(rt * 16 + l16) * 264 + kt * 32 + g * 8];
        const unsigned* Bk = BgB + ((long)kt * 4 + g) * 640 * 4;
        bf16x8 bfr[5];
        #pragma unroll
        for (int u = 0; u < 4; ++u)
            bfr[u] = *(const bf16x8*)&Bk[colR[u] * 4];
        bfr[4] = *(const bf16x8*)&Bk[col2 * 4];
        #pragma unroll
        for (int ci = 0; ci < 4; ++ci) {
            accR[ci][0] = __builtin_amdgcn_mfma_f32_16x16x32_bf16(af[0], bfr[ci], accR[ci][0], 0, 0, 0);
            accR[ci][1] = __builtin_amdgcn_mfma_f32_16x16x32_bf16(af[1], bfr[ci], accR[ci][1], 0, 0, 0);
        }
        #pragma unroll
        for (int rt = 0; rt < 4; ++rt)
            acc2[rt] = __builtin_amdgcn_mfma_f32_16x16x32_bf16(af[2 + rt], bfr[4], acc2[rt], 0, 0, 0);
    }

    // ---- pre-barrier: all epilogue contractions in registers ----
    float p3[3] = {0.f, 0.f, 0.f};
    {
        const int c = 128 + 16 * w + l16;
        #pragma unroll
        for (int rt = 0; rt < 4; ++rt) {
            #pragma unroll
            for (int e = 0; e < 4; ++e) {
                int l = rt * 16 + g * 4 + e;
                if (l < 63) {
                    int r3 = (l >= 42) ? 2 : ((l >= 21) ? 1 : 0);
                    int rr = l - 21 * r3;
                    float wgt = bfu2f((rr < 20) ? Wfb16[rr * 384 + c] : Wfb16[7680 + c]);
                    p3[r3] += wgt * acc2[rt][e];
                }
            }
        }
        #pragma unroll
        for (int r3 = 0; r3 < 3; ++r3) {
            p3[r3] += __shfl_xor(p3[r3], 16, 64);
            p3[r3] += __shfl_xor(p3[r3], 32, 64);
        }
    }
    float pq[4];
    #pragma unroll
    for (int ci = 0; ci < 4; ++ci) {
        const int cwf = (w < 2) ? colR[ci] : (256 + ((colR[ci] - 256) & 127));
        float p = 0.f;
        #pragma unroll
        for (int rt = 0; rt < 2; ++rt) {
            #pragma unroll
            for (int e = 0; e < 4; ++e) {
                int row = rt * 16 + g * 4 + e;
                if (row <= 20) {
                    float wgt = bfu2f((row < 20) ? Wfb16[row * 384 + cwf] : Wfb16[7680 + cwf]);
                    p += wgt * accR[ci][rt][e];
                }
            }
        }
        p += __shfl_xor(p, 16, 64);
        p += __shfl_xor(p, 32, 64);
        pq[ci] = p;
    }
    const float vpre = (t < 384) ? v_all[(long)bi * 384 + t] : 0.f;
    __syncthreads();   // A16 dead from here; aliased writes below are safe

    // ---- aliased LDS buffers on A16 (12672 f32 available) ----
    float* fb      = (float*)A16;
    float* dmuR_s  = fb;           // 384
    float* dmumu_s = fb + 384;     // 384
    float* q_s     = fb + 768;     // 128
    float* mu_s    = fb + 896;     // 384
    float* part    = fb + 1280;    // [2][768]
    float* muV     = fb + 2816;    // 384
    float* muW     = fb + 3200;    // 384
    float* ctx     = fb + 3584;    // 256
    float* o_part  = fb + 3840;    // [2][256]
    float* hsm     = fb + 4352;    // 128
    float* x2s     = fb + 4480;    // 384
    float* red     = fb + 4864;    // 8

    if (lane < 16) {
        #pragma unroll
        for (int r3 = 0; r3 < 3; ++r3) dmuR_s[r3 * 128 + 16 * w + l16] = p3[r3];
        #pragma unroll
        for (int ci = 0; ci < 4; ++ci) {
            if (w < 2) {
                q_s[colR[ci]] = s_all[bi * 128 + colR[ci]] + pq[ci];
            } else {
                dmumu_s[colR[ci] - 256] = pq[ci];
            }
        }
    }
    __syncthreads();
    if (t < 384) mu_s[t] = vpre + dmuR_s[t] + dmumu_s[t];
    __syncthreads();

    // ================= Phase C: mixing (uint2 packed-pair weight loads) =================
    const int c = t & 255, kh = t >> 8;
    float qv = (t < 128) ? q_s[t] : 0.f;

    // mu_mix: k4 covers 4 k-values
    {
        float m0 = 0.f, m1 = 0.f, m2 = 0.f;
        const int k40 = kh * 16;
        #pragma unroll 4
        for (int k4 = k40; k4 < k40 + 16; ++k4) {
            uint2 u = *(const uint2*)&Wmu_p[k4 * 512 + c * 2];
            const int k = 4 * k4;
            float w0 = lo2f(u.x), w1 = hi2f(u.x), w2 = lo2f(u.y), w3 = hi2f(u.y);
            m0 += mu_s[k] * w0 + mu_s[k + 1] * w1 + mu_s[k + 2] * w2 + mu_s[k + 3] * w3;
            m1 += mu_s[128 + k] * w0 + mu_s[128 + k + 1] * w1
                + mu_s[128 + k + 2] * w2 + mu_s[128 + k + 3] * w3;
            m2 += mu_s[256 + k] * w0 + mu_s[256 + k + 1] * w1
                + mu_s[256 + k + 2] * w2 + mu_s[256 + k + 3] * w3;
        }
        part[kh * 768 + c] = m0; part[kh * 768 + 256 + c] = m1; part[kh * 768 + 512 + c] = m2;
    }
    float ss = qv * qv;
    #pragma unroll
    for (int off = 32; off > 0; off >>= 1) ss += __shfl_xor(ss, off, 64);
    if ((t & 63) == 0) red[t >> 6] = ss;
    __syncthreads();
    for (int idx = t; idx < 768; idx += 512) {
        const int r3 = idx >> 8, cc = idx & 255;
        float val = part[idx] + part[768 + idx];
        if (cc < 128) muV[r3 * 128 + cc] = val;
        else          muW[r3 * 128 + (cc - 128)] = val;
    }
    __syncthreads();
    float mean = (red[0] + red[1] + red[2] + red[3] + red[4] + red[5] + red[6] + red[7])
                 * (1.0f / 128.0f);
    if (t < 128) {
        ctx[t] = qv * rsqrtf(mean + 1e-6f) * (1.0f + norm2_w[t]);
    } else if (t < 256) {
        int d2 = t - 128;
        ctx[t] = sqrtf(muV[d2] * muV[d2] + muV[128 + d2] * muV[128 + d2]
                       + muV[256 + d2] * muV[256 + d2] + 1e-6f);
    }
    __syncthreads();

    // o = ctx @ W_m1 (split-K halves, uint2, dual accumulators)
    {
        float acc0 = 0.f, acc1 = 0.f;
        const int k40 = kh * 32;
        #pragma unroll 8
        for (int k4 = k40; k4 < k40 + 32; ++k4) {
            uint2 u = *(const uint2*)&Wm1_p[k4 * 512 + c * 2];
            const int k = 4 * k4;
            acc0 += ctx[k] * lo2f(u.x) + ctx[k + 1] * hi2f(u.x);
            acc1 += ctx[k + 2] * lo2f(u.y) + ctx[k + 3] * hi2f(u.y);
        }
        o_part[kh * 256 + c] = acc0 + acc1;
    }
    __syncthreads();
    if (t < 128) {
        float a  = o_part[t]       + o_part[256 + t]       + b_m1[t];
        float gg = o_part[t + 128] + o_part[256 + t + 128] + b_m1[t + 128];
        hsm[t] = a * sigm(a) * sigm(gg);
    }
    __syncthreads();
    if (t < 384) {
        float a0 = b_m2[t], a1 = 0.f;
        #pragma unroll 8
        for (int k4 = 0; k4 < 32; ++k4) {
            uint2 u = *(const uint2*)&Wm2_p[k4 * 768 + t * 2];
            const int k = 4 * k4;
            a0 += hsm[k] * lo2f(u.x) + hsm[k + 1] * hi2f(u.x);
            a1 += hsm[k + 2] * lo2f(u.y) + hsm[k + 3] * hi2f(u.y);
        }
        x2s[t] = a0 + a1;
    }
    __syncthreads();

    if (t < 128) {
        const int d = t;
        float vw = muV[d] * muW[d] + muV[128 + d] * muW[128 + d] + muV[256 + d] * muW[256 + d];
        if (i < 192)
            q_out[((long)b * 192 + i) * 128 + d] = qv + x2s[d] + x2s[256 + d] * vw;
        #pragma unroll
        for (int r = 0; r < 3; ++r)
            mu_out[((long)bi * 3 + r) * 128 + d] =
                mu_s[r * 128 + d] + x2s[128 + d] * muW[r * 128 + d];
    }
}

extern "C" void kernel_launch(void* const* d_in, const int* in_sizes, int n_in,
                              void* d_out, int out_size, void* d_ws, size_t ws_size,
                              hipStream_t stream) {
    (void)in_sizes; (void)n_in; (void)out_size;
    const float* s_heavy  = (const float*)d_in[0];
    const float* v_all    = (const float*)d_in[1];
    const float* rbf      = (const float*)d_in[2];
    const float* dir_ij   = (const float*)d_in[3];
    const float* mask_ij  = (const float*)d_in[4];
    const int*   is_h     = (const int*)d_in[5];
    const float* h_emb    = (const float*)d_in[6];
    const float* W_filter = (const float*)d_in[7];
    const float* b_filter = (const float*)d_in[8];
    const float* norm1_w  = (const float*)d_in[9];
    const float* W_i1     = (const float*)d_in[10];
    const float* b_i1     = (const float*)d_in[11];
    const float* W_i2     = (const float*)d_in[12];
    const float* b_i2     = (const float*)d_in[13];
    const float* norm2_w  = (const float*)d_in[14];
    const float* W_m1     = (const float*)d_in[15];
    const float* b_m1     = (const float*)d_in[16];
    const float* W_m2     = (const float*)d_in[17];
    const float* b_m2     = (const float*)d_in[18];
    const float* W_mu     = (const float*)d_in[19];

    // ws layout (f32 units): s_all 0 | x 65536 | Bg 262144(+163840) | Wmu_p 425984(+16384)
    //  | Wm1_p 442368(+32768) | Wm2_p 475136(+24576) | Wfb_p 499712(+4032)
    const size_t need = (size_t)503744 * 4;
    if (ws_size < need) return;
    float* ws    = (float*)d_ws;
    float* s_all = ws;
    float* x     = ws + 65536;
    unsigned* Bg    = (unsigned*)(ws + 262144);
    unsigned* Wmu_p = (unsigned*)(ws + 425984);
    unsigned* Wm1_p = (unsigned*)(ws + 442368);
    unsigned* Wm2_p = (unsigned*)(ws + 475136);
    unsigned* Wfb_p = (unsigned*)(ws + 499712);

    float* q_out  = (float*)d_out;               // (2,192,128)
    float* mu_out = q_out + 2 * 192 * 128;       // (2,256,3,128)

    kA<<<576, 256, 0, stream>>>(s_heavy, is_h, h_emb, norm1_w, W_i1, b_i1, W_i2, b_i2,
                                W_mu, W_m1, W_m2, W_filter, b_filter,
                                s_all, x, Wmu_p, Wm1_p, Wm2_p, Wfb_p);
    kX2<<<64, 640, 0, stream>>>(x, v_all, Bg);
    kBC<<<512, 512, 0, stream>>>(rbf, dir_ij, mask_ij, v_all, s_all, Bg,
                                 Wmu_p, norm2_w, Wm1_p, b_m1, Wm2_p, b_m2, Wfb_p,
                                 q_out, mu_out);
}

// Round 18
// 44.612 us; speedup vs baseline: 1.5914x; 1.0470x over previous
//
#include <hip/hip_runtime.h>
#include <hip/hip_bf16.h>

#define DEV static __device__ __forceinline__

typedef __attribute__((ext_vector_type(8))) short bf16x8;
typedef __attribute__((ext_vector_type(4))) float f32x4;

DEV float sigm(float x) { return 1.0f / (1.0f + __expf(-x)); }

DEV unsigned pack2bf(float a, float b) {
    unsigned r;
    asm("v_cvt_pk_bf16_f32 %0, %1, %2" : "=v"(r) : "v"(a), "v"(b));
    return r;
}
DEV unsigned short f2bf(float a) {
    unsigned ua = __float_as_uint(a);
    return (unsigned short)((ua + 0x7FFF + ((ua >> 16) & 1)) >> 16);
}
DEV float bfu2f(unsigned short u) { return __uint_as_float(((unsigned)u) << 16); }
DEV float lo2f(unsigned u) { return __uint_as_float(u << 16); }
DEV float hi2f(unsigned u) { return __uint_as_float(u & 0xffff0000u); }

// B=2, N=256, Nh=192, D=128, R=20
// Bg: uint4 per (b, kt, g, col) = 8 bf16 along j. kA atom block bi (j = bi&255) writes
// its j-slot u16 into each of its 640 uint4s directly (disjoint bytes across blocks).

// Kernel A: blocks <512: per-atom s_all + x + Bg row. blocks 512..575: pack mixing weights.
__global__ __launch_bounds__(256) void kA(
    const float* __restrict__ s_heavy, const int* __restrict__ is_h,
    const float* __restrict__ h_emb, const float* __restrict__ norm1_w,
    const float* __restrict__ W_i1, const float* __restrict__ b_i1,
    const float* __restrict__ W_i2, const float* __restrict__ b_i2,
    const float* __restrict__ W_mu, const float* __restrict__ W_m1,
    const float* __restrict__ W_m2, const float* __restrict__ W_filter,
    const float* __restrict__ b_filter, const float* __restrict__ v_all,
    float* __restrict__ s_all, float* __restrict__ x,
    unsigned short* __restrict__ Bg16,
    unsigned* __restrict__ Wmu_p, unsigned* __restrict__ Wm1_p,
    unsigned* __restrict__ Wm2_p, unsigned* __restrict__ Wfb_p)
{
    const int blk = blockIdx.x;
    const int t = threadIdx.x;
    if (blk >= 512) {
        const int idx0 = (blk - 512) * 256 + t;       // 0..16383
        {   // W_mu: k2 in [0,64), c in [0,256)
            int k2 = idx0 >> 8, c = idx0 & 255;
            Wmu_p[(k2 >> 1) * 512 + c * 2 + (k2 & 1)] =
                pack2bf(W_mu[(2 * k2) * 256 + c], W_mu[(2 * k2 + 1) * 256 + c]);
        }
        #pragma unroll
        for (int r = 0; r < 2; ++r) {                 // W_m1: k2 in [0,128)
            int s = idx0 + r * 16384;
            int k2 = s >> 8, c = s & 255;
            Wm1_p[(k2 >> 1) * 512 + c * 2 + (k2 & 1)] =
                pack2bf(W_m1[(2 * k2) * 256 + c], W_m1[(2 * k2 + 1) * 256 + c]);
        }
        for (int s = idx0; s < 24576; s += 16384) {   // W_m2: k2 in [0,64), c in [0,384)
            int k2 = s / 384, c = s - k2 * 384;
            Wm2_p[(k2 >> 1) * 768 + c * 2 + (k2 & 1)] =
                pack2bf(W_m2[(2 * k2) * 384 + c], W_m2[(2 * k2 + 1) * 384 + c]);
        }
        for (int s = idx0; s < 4032; s += 16384) {    // [W_filter(7680) | b_filter(384)] u16
            int e = 2 * s;
            float v0 = (e < 7680) ? W_filter[e] : b_filter[e - 7680];
            float v1 = (e + 1 < 7680) ? W_filter[e + 1] : b_filter[e + 1 - 7680];
            Wfb_p[s] = pack2bf(v0, v1);
        }
        return;
    }
    const int bi = blk;
    const int b = bi >> 8, i = bi & 255;
    __shared__ float y[128];
    __shared__ float o[256];
    __shared__ float h[128];
    __shared__ float xrow[384];
    __shared__ float red[4];

    float s = 0.f;
    if (t < 128) {
        if (is_h[bi] != 0) s = h_emb[t];
        else if (i < 192) s = s_heavy[(b * 192 + i) * 128 + t];
        s_all[bi * 128 + t] = s;
    }
    float ss = s * s;
    #pragma unroll
    for (int off = 32; off > 0; off >>= 1) ss += __shfl_xor(ss, off, 64);
    if ((t & 63) == 0) red[t >> 6] = ss;
    __syncthreads();
    float v = (red[0] + red[1] + red[2] + red[3]) * (1.0f / 128.0f);
    float inv = rsqrtf(v + 1e-6f);
    if (t < 128) y[t] = s * inv * (1.0f + norm1_w[t]);
    __syncthreads();

    {
        float acc0 = 0.f, acc1 = 0.f;
        #pragma unroll 8
        for (int k = 0; k < 128; k += 2) {
            acc0 += y[k] * W_i1[k * 256 + t];
            acc1 += y[k + 1] * W_i1[(k + 1) * 256 + t];
        }
        o[t] = acc0 + acc1 + b_i1[t];
    }
    __syncthreads();
    if (t < 128) {
        float a = o[t], g = o[t + 128];
        h[t] = a * sigm(a) * sigm(g);
    }
    __syncthreads();
    for (int c = t; c < 384; c += 256) {
        float a0 = b_i2[c], a1 = 0.f;
        #pragma unroll 8
        for (int k = 0; k < 128; k += 2) {
            a0 += h[k] * W_i2[k * 384 + c];
            a1 += h[k + 1] * W_i2[(k + 1) * 384 + c];
        }
        float xv = a0 + a1;
        x[(long)bi * 384 + c] = xv;
        xrow[c] = xv;
    }
    __syncthreads();

    // ---- Bg row write: j = i; slot jj = i&7 within uint4 (b, kt=i>>5, g=(i>>3)&3, col) ----
    {
        const int j = i;
        const int kt = j >> 5, g2 = (j >> 3) & 3, jj = j & 7;
        const long base16 = (((long)(b * 8 + kt) * 4 + g2) * 640) * 8 + jj;  // u16 units
        for (int col = t; col < 640; col += 256) {
            float val;
            if (col < 256) val = xrow[col];
            else {
                const int cg = col - 256;
                val = v_all[(long)bi * 384 + cg] * xrow[256 + (cg & 127)];
            }
            Bg16[base16 + col * 8] = f2bf(val);
        }
    }
}

// Kernel BC (fused B+C), 53248 B LDS; (512,4) -> VGPR<=64, 3 blocks/CU via LDS.
__global__ __launch_bounds__(512, 4) void kBC(
    const float* __restrict__ rbf, const float* __restrict__ dir_ij,
    const float* __restrict__ mask_ij, const float* __restrict__ v_all,
    const float* __restrict__ s_all, const unsigned* __restrict__ Bg,
    const unsigned* __restrict__ Wmu_p, const float* __restrict__ norm2_w,
    const unsigned* __restrict__ Wm1_p, const float* __restrict__ b_m1,
    const unsigned* __restrict__ Wm2_p, const float* __restrict__ b_m2,
    const unsigned* __restrict__ Wfb_p,
    float* __restrict__ q_out, float* __restrict__ mu_out)
{
    const int bi = blockIdx.x, b = bi >> 8, i = bi & 255;
    const int t = threadIdx.x;
    const int lane = t & 63, w = t >> 6, g = lane >> 4, l16 = lane & 15;

    __shared__ __align__(16) unsigned short A16[96 * 264];  // 50688 B
    __shared__ unsigned short dir16[768];                   // 1536 B
    __shared__ float m_s[256];                              // 1024 B

    // ---- pass 1: stage m, dir16 (bf16); zero pad rows 21-31, 95 ----
    if (t < 256) m_s[t] = mask_ij[(long)bi * 256 + t];
    for (int idx = t; idx < 768; idx += 512) dir16[idx] = f2bf(dir_ij[(long)bi * 768 + idx]);
    {
        unsigned* Az = (unsigned*)A16;
        for (int s2 = t; s2 < 1452; s2 += 512) Az[2772 + s2] = 0;   // rows 21-31
        if (t < 132) Az[12540 + t] = 0;                              // row 95
    }
    __syncthreads();

    // ---- pass 2: even-j paired rbf load + A build (u32 writes, cvt_pk) ----
    {
        unsigned* A32 = (unsigned*)A16;
        #pragma unroll
        for (int it = 0; it < 5; ++it) {
            const int idx = it * 512 + t;            // 0..2559
            const int j2 = idx / 20, r = idx - j2 * 20;
            const int j = 2 * j2;
            const float v0 = rbf[(long)bi * 5120 + j2 * 40 + r];
            const float v1 = rbf[(long)bi * 5120 + j2 * 40 + 20 + r];
            const float vm0 = v0 * m_s[j], vm1 = v1 * m_s[j + 1];
            const float d00 = bfu2f(dir16[j * 3 + 0]), d01 = bfu2f(dir16[j * 3 + 3]);
            const float d10 = bfu2f(dir16[j * 3 + 1]), d11 = bfu2f(dir16[j * 3 + 4]);
            const float d20 = bfu2f(dir16[j * 3 + 2]), d21 = bfu2f(dir16[j * 3 + 5]);
            A32[r * 132 + j2]        = pack2bf(vm0, vm1);
            A32[(32 + r) * 132 + j2] = pack2bf(vm0 * d00, vm1 * d01);
            A32[(53 + r) * 132 + j2] = pack2bf(vm0 * d10, vm1 * d11);
            A32[(74 + r) * 132 + j2] = pack2bf(vm0 * d20, vm1 * d21);
        }
        if (t < 128) {   // mask rows: 20, 52, 73, 94 (j-pairs)
            const int j2 = t, j = 2 * t;
            const float m0 = m_s[j], m1 = m_s[j + 1];
            const float d00 = bfu2f(dir16[j * 3 + 0]), d01 = bfu2f(dir16[j * 3 + 3]);
            const float d10 = bfu2f(dir16[j * 3 + 1]), d11 = bfu2f(dir16[j * 3 + 4]);
            const float d20 = bfu2f(dir16[j * 3 + 2]), d21 = bfu2f(dir16[j * 3 + 5]);
            A32[20 * 132 + j2] = pack2bf(m0, m1);
            A32[52 * 132 + j2] = pack2bf(m0 * d00, m1 * d01);
            A32[73 * 132 + j2] = pack2bf(m0 * d10, m1 * d11);
            A32[94 * 132 + j2] = pack2bf(m0 * d20, m1 * d21);
        }
    }
    __syncthreads();

    // ---- tile assignment ----
    int colR[4];
    #pragma unroll
    for (int ci = 0; ci < 4; ++ci) {
        int ct = (w < 2) ? (4 * w + ci) : (4 * w + 8 + ci);
        colR[ci] = ct * 16 + l16;
    }
    const int col2 = (8 + w) * 16 + l16;

    const unsigned* BgB = Bg + (long)b * 81920;
    const unsigned short* Wfb16 = (const unsigned short*)Wfb_p;

    f32x4 accR[4][2];
    f32x4 acc2[4];
    #pragma unroll
    for (int ci = 0; ci < 4; ++ci) {
        #pragma unroll
        for (int rt = 0; rt < 2; ++rt) accR[ci][rt] = {0.f, 0.f, 0.f, 0.f};
        acc2[ci] = {0.f, 0.f, 0.f, 0.f};
    }

    // ---- GEMM: K = 256 j = 8 k-steps of 32 ----
    #pragma unroll 2
    for (int kt = 0; kt < 8; ++kt) {
        bf16x8 af[6];
        #pragma unroll
        for (int rt = 0; rt < 6; ++rt)
            af[rt] = *(const bf16x8*)&A16[(rt * 16 + l16) * 264 + kt * 32 + g * 8];
        const unsigned* Bk = BgB + ((long)kt * 4 + g) * 640 * 4;
        bf16x8 bfr[5];
        #pragma unroll
        for (int u = 0; u < 4; ++u)
            bfr[u] = *(const bf16x8*)&Bk[colR[u] * 4];
        bfr[4] = *(const bf16x8*)&Bk[col2 * 4];
        #pragma unroll
        for (int ci = 0; ci < 4; ++ci) {
            accR[ci][0] = __builtin_amdgcn_mfma_f32_16x16x32_bf16(af[0], bfr[ci], accR[ci][0], 0, 0, 0);
            accR[ci][1] = __builtin_amdgcn_mfma_f32_16x16x32_bf16(af[1], bfr[ci], accR[ci][1], 0, 0, 0);
        }
        #pragma unroll
        for (int rt = 0; rt < 4; ++rt)
            acc2[rt] = __builtin_amdgcn_mfma_f32_16x16x32_bf16(af[2 + rt], bfr[4], acc2[rt], 0, 0, 0);
    }

    // ---- pre-barrier: all epilogue contractions in registers ----
    float p3[3] = {0.f, 0.f, 0.f};
    {
        const int c = 128 + 16 * w + l16;
        #pragma unroll
        for (int rt = 0; rt < 4; ++rt) {
            #pragma unroll
            for (int e = 0; e < 4; ++e) {
                int l = rt * 16 + g * 4 + e;
                if (l < 63) {
                    int r3 = (l >= 42) ? 2 : ((l >= 21) ? 1 : 0);
                    int rr = l - 21 * r3;
                    float wgt = bfu2f((rr < 20) ? Wfb16[rr * 384 + c] : Wfb16[7680 + c]);
                    p3[r3] += wgt * acc2[rt][e];
                }
            }
        }
        #pragma unroll
        for (int r3 = 0; r3 < 3; ++r3) {
            p3[r3] += __shfl_xor(p3[r3], 16, 64);
            p3[r3] += __shfl_xor(p3[r3], 32, 64);
        }
    }
    float pq[4];
    #pragma unroll
    for (int ci = 0; ci < 4; ++ci) {
        const int cwf = (w < 2) ? colR[ci] : (256 + ((colR[ci] - 256) & 127));
        float p = 0.f;
        #pragma unroll
        for (int rt = 0; rt < 2; ++rt) {
            #pragma unroll
            for (int e = 0; e < 4; ++e) {
                int row = rt * 16 + g * 4 + e;
                if (row <= 20) {
                    float wgt = bfu2f((row < 20) ? Wfb16[row * 384 + cwf] : Wfb16[7680 + cwf]);
                    p += wgt * accR[ci][rt][e];
                }
            }
        }
        p += __shfl_xor(p, 16, 64);
        p += __shfl_xor(p, 32, 64);
        pq[ci] = p;
    }
    const float vpre = (t < 384) ? v_all[(long)bi * 384 + t] : 0.f;
    __syncthreads();   // A16 dead from here; aliased writes below are safe

    // ---- aliased LDS buffers on A16 (12672 f32 available) ----
    float* fb      = (float*)A16;
    float* dmuR_s  = fb;           // 384
    float* dmumu_s = fb + 384;     // 384
    float* q_s     = fb + 768;     // 128
    float* mu_s    = fb + 896;     // 384 (16B aligned: 896*4=3584)
    float* part    = fb + 1280;    // [2][768]
    float* muV     = fb + 2816;    // 384
    float* muW     = fb + 3200;    // 384
    float* ctx     = fb + 3584;    // 256 (16B aligned)
    float* o_part  = fb + 3840;    // [2][256]
    float* hsm     = fb + 4352;    // 128 (16B aligned)
    float* x2s     = fb + 4480;    // 384
    float* red     = fb + 4864;    // 8

    if (lane < 16) {
        #pragma unroll
        for (int r3 = 0; r3 < 3; ++r3) dmuR_s[r3 * 128 + 16 * w + l16] = p3[r3];
        #pragma unroll
        for (int ci = 0; ci < 4; ++ci) {
            if (w < 2) {
                q_s[colR[ci]] = s_all[bi * 128 + colR[ci]] + pq[ci];
            } else {
                dmumu_s[colR[ci] - 256] = pq[ci];
            }
        }
    }
    __syncthreads();
    if (t < 384) mu_s[t] = vpre + dmuR_s[t] + dmumu_s[t];
    __syncthreads();

    // ================= Phase C: mixing (uint2 weights, float4 LDS reads) =================
    const int c = t & 255, kh = t >> 8;
    float qv = (t < 128) ? q_s[t] : 0.f;

    {
        float m0 = 0.f, m1 = 0.f, m2 = 0.f;
        const int k40 = kh * 16;
        #pragma unroll 4
        for (int k4 = k40; k4 < k40 + 16; ++k4) {
            uint2 u = *(const uint2*)&Wmu_p[k4 * 512 + c * 2];
            const int k = 4 * k4;
            float4 a0 = *(const float4*)&mu_s[k];
            float4 a1 = *(const float4*)&mu_s[128 + k];
            float4 a2 = *(const float4*)&mu_s[256 + k];
            float w0 = lo2f(u.x), w1 = hi2f(u.x), w2 = lo2f(u.y), w3 = hi2f(u.y);
            m0 += a0.x * w0 + a0.y * w1 + a0.z * w2 + a0.w * w3;
            m1 += a1.x * w0 + a1.y * w1 + a1.z * w2 + a1.w * w3;
            m2 += a2.x * w0 + a2.y * w1 + a2.z * w2 + a2.w * w3;
        }
        part[kh * 768 + c] = m0; part[kh * 768 + 256 + c] = m1; part[kh * 768 + 512 + c] = m2;
    }
    float ss = qv * qv;
    #pragma unroll
    for (int off = 32; off > 0; off >>= 1) ss += __shfl_xor(ss, off, 64);
    if ((t & 63) == 0) red[t >> 6] = ss;
    __syncthreads();
    for (int idx = t; idx < 768; idx += 512) {
        const int r3 = idx >> 8, cc = idx & 255;
        float val = part[idx] + part[768 + idx];
        if (cc < 128) muV[r3 * 128 + cc] = val;
        else          muW[r3 * 128 + (cc - 128)] = val;
    }
    __syncthreads();
    float mean = (red[0] + red[1] + red[2] + red[3] + red[4] + red[5] + red[6] + red[7])
                 * (1.0f / 128.0f);
    if (t < 128) {
        ctx[t] = qv * rsqrtf(mean + 1e-6f) * (1.0f + norm2_w[t]);
    } else if (t < 256) {
        int d2 = t - 128;
        ctx[t] = sqrtf(muV[d2] * muV[d2] + muV[128 + d2] * muV[128 + d2]
                       + muV[256 + d2] * muV[256 + d2] + 1e-6f);
    }
    __syncthreads();

    {
        float acc0 = 0.f, acc1 = 0.f;
        const int k40 = kh * 32;
        #pragma unroll 8
        for (int k4 = k40; k4 < k40 + 32; ++k4) {
            uint2 u = *(const uint2*)&Wm1_p[k4 * 512 + c * 2];
            float4 cx = *(const float4*)&ctx[4 * k4];
            acc0 += cx.x * lo2f(u.x) + cx.y * hi2f(u.x);
            acc1 += cx.z * lo2f(u.y) + cx.w * hi2f(u.y);
        }
        o_part[kh * 256 + c] = acc0 + acc1;
    }
    __syncthreads();
    if (t < 128) {
        float a  = o_part[t]       + o_part[256 + t]       + b_m1[t];
        float gg = o_part[t + 128] + o_part[256 + t + 128] + b_m1[t + 128];
        hsm[t] = a * sigm(a) * sigm(gg);
    }
    __syncthreads();
    if (t < 384) {
        float a0 = b_m2[t], a1 = 0.f;
        #pragma unroll 8
        for (int k4 = 0; k4 < 32; ++k4) {
            uint2 u = *(const uint2*)&Wm2_p[k4 * 768 + t * 2];
            float4 hx = *(const float4*)&hsm[4 * k4];
            a0 += hx.x * lo2f(u.x) + hx.y * hi2f(u.x);
            a1 += hx.z * lo2f(u.y) + hx.w * hi2f(u.y);
        }
        x2s[t] = a0 + a1;
    }
    __syncthreads();

    if (t < 128) {
        const int d = t;
        float vw = muV[d] * muW[d] + muV[128 + d] * muW[128 + d] + muV[256 + d] * muW[256 + d];
        if (i < 192)
            q_out[((long)b * 192 + i) * 128 + d] = qv + x2s[d] + x2s[256 + d] * vw;
        #pragma unroll
        for (int r = 0; r < 3; ++r)
            mu_out[((long)bi * 3 + r) * 128 + d] =
                mu_s[r * 128 + d] + x2s[128 + d] * muW[r * 128 + d];
    }
}

extern "C" void kernel_launch(void* const* d_in, const int* in_sizes, int n_in,
                              void* d_out, int out_size, void* d_ws, size_t ws_size,
                              hipStream_t stream) {
    (void)in_sizes; (void)n_in; (void)out_size;
    const float* s_heavy  = (const float*)d_in[0];
    const float* v_all    = (const float*)d_in[1];
    const float* rbf      = (const float*)d_in[2];
    const float* dir_ij   = (const float*)d_in[3];
    const float* mask_ij  = (const float*)d_in[4];
    const int*   is_h     = (const int*)d_in[5];
    const float* h_emb    = (const float*)d_in[6];
    const float* W_filter = (const float*)d_in[7];
    const float* b_filter = (const float*)d_in[8];
    const float* norm1_w  = (const float*)d_in[9];
    const float* W_i1     = (const float*)d_in[10];
    const float* b_i1     = (const float*)d_in[11];
    const float* W_i2     = (const float*)d_in[12];
    const float* b_i2     = (const float*)d_in[13];
    const float* norm2_w  = (const float*)d_in[14];
    const float* W_m1     = (const float*)d_in[15];
    const float* b_m1     = (const float*)d_in[16];
    const float* W_m2     = (const float*)d_in[17];
    const float* b_m2     = (const float*)d_in[18];
    const float* W_mu     = (const float*)d_in[19];

    // ws layout (f32 units): s_all 0 | x 65536 | Bg 262144(+163840) | Wmu_p 425984(+16384)
    //  | Wm1_p 442368(+32768) | Wm2_p 475136(+24576) | Wfb_p 499712(+4032)
    const size_t need = (size_t)503744 * 4;
    if (ws_size < need) return;
    float* ws    = (float*)d_ws;
    float* s_all = ws;
    float* x     = ws + 65536;
    unsigned* Bg    = (unsigned*)(ws + 262144);
    unsigned* Wmu_p = (unsigned*)(ws + 425984);
    unsigned* Wm1_p = (unsigned*)(ws + 442368);
    unsigned* Wm2_p = (unsigned*)(ws + 475136);
    unsigned* Wfb_p = (unsigned*)(ws + 499712);

    float* q_out  = (float*)d_out;               // (2,192,128)
    float* mu_out = q_out + 2 * 192 * 128;       // (2,256,3,128)

    kA<<<576, 256, 0, stream>>>(s_heavy, is_h, h_emb, norm1_w, W_i1, b_i1, W_i2, b_i2,
                                W_mu, W_m1, W_m2, W_filter, b_filter, v_all,
                                s_all, x, (unsigned short*)Bg,
                                Wmu_p, Wm1_p, Wm2_p, Wfb_p);
    kBC<<<512, 512, 0, stream>>>(rbf, dir_ij, mask_ij, v_all, s_all, Bg,
                                 Wmu_p, norm2_w, Wm1_p, b_m1, Wm2_p, b_m2, Wfb_p,
                                 q_out, mu_out);
}

// Round 19
// 42.572 us; speedup vs baseline: 1.6677x; 1.0479x over previous
//
#include <hip/hip_runtime.h>
#include <hip/hip_bf16.h>

#define DEV static __device__ __forceinline__

typedef __attribute__((ext_vector_type(8))) short bf16x8;
typedef __attribute__((ext_vector_type(4))) float f32x4;

DEV float sigm(float x) { return 1.0f / (1.0f + __expf(-x)); }

DEV unsigned pack2bf(float a, float b) {
    unsigned r;
    asm("v_cvt_pk_bf16_f32 %0, %1, %2" : "=v"(r) : "v"(a), "v"(b));
    return r;
}
DEV unsigned short f2bf(float a) {
    unsigned ua = __float_as_uint(a);
    return (unsigned short)((ua + 0x7FFF + ((ua >> 16) & 1)) >> 16);
}
DEV float bfu2f(unsigned short u) { return __uint_as_float(((unsigned)u) << 16); }
DEV float lo2f(unsigned u) { return __uint_as_float(u << 16); }
DEV float hi2f(unsigned u) { return __uint_as_float(u & 0xffff0000u); }

// B=2, N=256, Nh=192, D=128, R=20
// Bg: uint4 per (b, kt, g, col) = 8 bf16 along j. kA atom block bi (j = bi&255) writes
// its j-slot u16 into each of its 640 uint4s directly (disjoint bytes across blocks).

// Kernel A: blocks <512 (512 thr): per-atom s_all + x-row + Bg row.
//           blocks 512..543 (512 thr): pack mixing weights to bf16.
__global__ __launch_bounds__(512) void kA(
    const float* __restrict__ s_heavy, const int* __restrict__ is_h,
    const float* __restrict__ h_emb, const float* __restrict__ norm1_w,
    const float* __restrict__ W_i1, const float* __restrict__ b_i1,
    const float* __restrict__ W_i2, const float* __restrict__ b_i2,
    const float* __restrict__ W_mu, const float* __restrict__ W_m1,
    const float* __restrict__ W_m2, const float* __restrict__ W_filter,
    const float* __restrict__ b_filter, const float* __restrict__ v_all,
    float* __restrict__ s_all,
    unsigned short* __restrict__ Bg16,
    unsigned* __restrict__ Wmu_p, unsigned* __restrict__ Wm1_p,
    unsigned* __restrict__ Wm2_p, unsigned* __restrict__ Wfb_p)
{
    const int blk = blockIdx.x;
    const int t = threadIdx.x;
    if (blk >= 512) {
        const int idx0 = (blk - 512) * 512 + t;       // 0..16383
        {   // W_mu: k2 in [0,64), c in [0,256)
            int k2 = idx0 >> 8, c = idx0 & 255;
            Wmu_p[(k2 >> 1) * 512 + c * 2 + (k2 & 1)] =
                pack2bf(W_mu[(2 * k2) * 256 + c], W_mu[(2 * k2 + 1) * 256 + c]);
        }
        #pragma unroll
        for (int r = 0; r < 2; ++r) {                 // W_m1: k2 in [0,128)
            int s = idx0 + r * 16384;
            int k2 = s >> 8, c = s & 255;
            Wm1_p[(k2 >> 1) * 512 + c * 2 + (k2 & 1)] =
                pack2bf(W_m1[(2 * k2) * 256 + c], W_m1[(2 * k2 + 1) * 256 + c]);
        }
        for (int s = idx0; s < 24576; s += 16384) {   // W_m2: k2 in [0,64), c in [0,384)
            int k2 = s / 384, c = s - k2 * 384;
            Wm2_p[(k2 >> 1) * 768 + c * 2 + (k2 & 1)] =
                pack2bf(W_m2[(2 * k2) * 384 + c], W_m2[(2 * k2 + 1) * 384 + c]);
        }
        for (int s = idx0; s < 4032; s += 16384) {    // [W_filter(7680) | b_filter(384)] u16
            int e = 2 * s;
            float v0 = (e < 7680) ? W_filter[e] : b_filter[e - 7680];
            float v1 = (e + 1 < 7680) ? W_filter[e + 1] : b_filter[e + 1 - 7680];
            Wfb_p[s] = pack2bf(v0, v1);
        }
        return;
    }
    const int bi = blk;
    const int b = bi >> 8, i = bi & 255;
    __shared__ float y[128];
    __shared__ float o_part[512];
    __shared__ float h[128];
    __shared__ float xrow[384];
    __shared__ float red[8];

    float s = 0.f;
    if (t < 128) {
        if (is_h[bi] != 0) s = h_emb[t];
        else if (i < 192) s = s_heavy[(b * 192 + i) * 128 + t];
        s_all[bi * 128 + t] = s;
    }
    float ss = s * s;
    #pragma unroll
    for (int off = 32; off > 0; off >>= 1) ss += __shfl_xor(ss, off, 64);
    if ((t & 63) == 0) red[t >> 6] = ss;
    __syncthreads();
    float v = (red[0] + red[1] + red[2] + red[3]
               + red[4] + red[5] + red[6] + red[7]) * (1.0f / 128.0f);
    float inv = rsqrtf(v + 1e-6f);
    if (t < 128) y[t] = s * inv * (1.0f + norm1_w[t]);
    __syncthreads();

    // o = y @ W_i1 (split-K halves over 512 threads)
    {
        const int c = t & 255, kh = t >> 8;
        float acc0 = 0.f, acc1 = 0.f;
        const int k0 = kh * 64;
        #pragma unroll 8
        for (int k = k0; k < k0 + 64; k += 2) {
            acc0 += y[k] * W_i1[k * 256 + c];
            acc1 += y[k + 1] * W_i1[(k + 1) * 256 + c];
        }
        o_part[kh * 256 + c] = acc0 + acc1;
    }
    __syncthreads();
    if (t < 128) {
        float a  = o_part[t]       + o_part[256 + t]       + b_i1[t];
        float gg = o_part[t + 128] + o_part[256 + t + 128] + b_i1[t + 128];
        h[t] = a * sigm(a) * sigm(gg);
    }
    __syncthreads();
    if (t < 384) {
        float a0 = b_i2[t], a1 = 0.f;
        #pragma unroll 8
        for (int k = 0; k < 128; k += 2) {
            a0 += h[k] * W_i2[k * 384 + t];
            a1 += h[k + 1] * W_i2[(k + 1) * 384 + t];
        }
        xrow[t] = a0 + a1;
    }
    __syncthreads();

    // ---- Bg row write: j = i; slot jj = i&7 within uint4 (b, kt=i>>5, g=(i>>3)&3, col) ----
    {
        const int j = i;
        const int kt = j >> 5, g2 = (j >> 3) & 3, jj = j & 7;
        const long base16 = (((long)(b * 8 + kt) * 4 + g2) * 640) * 8 + jj;  // u16 units
        for (int col = t; col < 640; col += 512) {
            float val;
            if (col < 256) val = xrow[col];
            else {
                const int cg = col - 256;
                val = v_all[(long)bi * 384 + cg] * xrow[256 + (cg & 127)];
            }
            Bg16[base16 + col * 8] = f2bf(val);
        }
    }
}

// Kernel BC (fused B+C), 53248 B LDS; (512,4) -> VGPR<=64, 3 blocks/CU via LDS.
__global__ __launch_bounds__(512, 4) void kBC(
    const float* __restrict__ rbf, const float* __restrict__ dir_ij,
    const float* __restrict__ mask_ij, const float* __restrict__ v_all,
    const float* __restrict__ s_all, const unsigned* __restrict__ Bg,
    const unsigned* __restrict__ Wmu_p, const float* __restrict__ norm2_w,
    const unsigned* __restrict__ Wm1_p, const float* __restrict__ b_m1,
    const unsigned* __restrict__ Wm2_p, const float* __restrict__ b_m2,
    const unsigned* __restrict__ Wfb_p,
    float* __restrict__ q_out, float* __restrict__ mu_out)
{
    const int bi = blockIdx.x, b = bi >> 8, i = bi & 255;
    const int t = threadIdx.x;
    const int lane = t & 63, w = t >> 6, g = lane >> 4, l16 = lane & 15;

    __shared__ __align__(16) unsigned short A16[96 * 264];  // 50688 B
    __shared__ unsigned short dir16[768];                   // 1536 B
    __shared__ float m_s[256];                              // 1024 B

    // ---- pass 1: stage m, dir16 (bf16); zero pad rows 21-31, 95 ----
    if (t < 256) m_s[t] = mask_ij[(long)bi * 256 + t];
    for (int idx = t; idx < 768; idx += 512) dir16[idx] = f2bf(dir_ij[(long)bi * 768 + idx]);
    {
        unsigned* Az = (unsigned*)A16;
        for (int s2 = t; s2 < 1452; s2 += 512) Az[2772 + s2] = 0;   // rows 21-31
        if (t < 132) Az[12540 + t] = 0;                              // row 95
    }
    __syncthreads();

    // ---- pass 2: even-j paired rbf load + A build (u32 writes, cvt_pk) ----
    {
        unsigned* A32 = (unsigned*)A16;
        #pragma unroll
        for (int it = 0; it < 5; ++it) {
            const int idx = it * 512 + t;            // 0..2559
            const int j2 = idx / 20, r = idx - j2 * 20;
            const int j = 2 * j2;
            const float v0 = rbf[(long)bi * 5120 + j2 * 40 + r];
            const float v1 = rbf[(long)bi * 5120 + j2 * 40 + 20 + r];
            const float vm0 = v0 * m_s[j], vm1 = v1 * m_s[j + 1];
            const float d00 = bfu2f(dir16[j * 3 + 0]), d01 = bfu2f(dir16[j * 3 + 3]);
            const float d10 = bfu2f(dir16[j * 3 + 1]), d11 = bfu2f(dir16[j * 3 + 4]);
            const float d20 = bfu2f(dir16[j * 3 + 2]), d21 = bfu2f(dir16[j * 3 + 5]);
            A32[r * 132 + j2]        = pack2bf(vm0, vm1);
            A32[(32 + r) * 132 + j2] = pack2bf(vm0 * d00, vm1 * d01);
            A32[(53 + r) * 132 + j2] = pack2bf(vm0 * d10, vm1 * d11);
            A32[(74 + r) * 132 + j2] = pack2bf(vm0 * d20, vm1 * d21);
        }
        if (t < 128) {   // mask rows: 20, 52, 73, 94 (j-pairs)
            const int j2 = t, j = 2 * t;
            const float m0 = m_s[j], m1 = m_s[j + 1];
            const float d00 = bfu2f(dir16[j * 3 + 0]), d01 = bfu2f(dir16[j * 3 + 3]);
            const float d10 = bfu2f(dir16[j * 3 + 1]), d11 = bfu2f(dir16[j * 3 + 4]);
            const float d20 = bfu2f(dir16[j * 3 + 2]), d21 = bfu2f(dir16[j * 3 + 5]);
            A32[20 * 132 + j2] = pack2bf(m0, m1);
            A32[52 * 132 + j2] = pack2bf(m0 * d00, m1 * d01);
            A32[73 * 132 + j2] = pack2bf(m0 * d10, m1 * d11);
            A32[94 * 132 + j2] = pack2bf(m0 * d20, m1 * d21);
        }
    }
    __syncthreads();

    // ---- tile assignment ----
    int colR[4];
    #pragma unroll
    for (int ci = 0; ci < 4; ++ci) {
        int ct = (w < 2) ? (4 * w + ci) : (4 * w + 8 + ci);
        colR[ci] = ct * 16 + l16;
    }
    const int col2 = (8 + w) * 16 + l16;

    const unsigned* BgB = Bg + (long)b * 81920;
    const unsigned short* Wfb16 = (const unsigned short*)Wfb_p;

    f32x4 accR[4][2];
    f32x4 acc2[4];
    #pragma unroll
    for (int ci = 0; ci < 4; ++ci) {
        #pragma unroll
        for (int rt = 0; rt < 2; ++rt) accR[ci][rt] = {0.f, 0.f, 0.f, 0.f};
        acc2[ci] = {0.f, 0.f, 0.f, 0.f};
    }

    // ---- GEMM: K = 256 j = 8 k-steps of 32 (setprio around MFMA cluster) ----
    __builtin_amdgcn_s_setprio(1);
    #pragma unroll 2
    for (int kt = 0; kt < 8; ++kt) {
        bf16x8 af[6];
        #pragma unroll
        for (int rt = 0; rt < 6; ++rt)
            af[rt] = *(const bf16x8*)&A16[(rt * 16 + l16) * 264 + kt * 32 + g * 8];
        const unsigned* Bk = BgB + ((long)kt * 4 + g) * 640 * 4;
        bf16x8 bfr[5];
        #pragma unroll
        for (int u = 0; u < 4; ++u)
            bfr[u] = *(const bf16x8*)&Bk[colR[u] * 4];
        bfr[4] = *(const bf16x8*)&Bk[col2 * 4];
        #pragma unroll
        for (int ci = 0; ci < 4; ++ci) {
            accR[ci][0] = __builtin_amdgcn_mfma_f32_16x16x32_bf16(af[0], bfr[ci], accR[ci][0], 0, 0, 0);
            accR[ci][1] = __builtin_amdgcn_mfma_f32_16x16x32_bf16(af[1], bfr[ci], accR[ci][1], 0, 0, 0);
        }
        #pragma unroll
        for (int rt = 0; rt < 4; ++rt)
            acc2[rt] = __builtin_amdgcn_mfma_f32_16x16x32_bf16(af[2 + rt], bfr[4], acc2[rt], 0, 0, 0);
    }
    __builtin_amdgcn_s_setprio(0);

    // ---- pre-barrier: all epilogue contractions in registers ----
    float p3[3] = {0.f, 0.f, 0.f};
    {
        const int c = 128 + 16 * w + l16;
        #pragma unroll
        for (int rt = 0; rt < 4; ++rt) {
            #pragma unroll
            for (int e = 0; e < 4; ++e) {
                int l = rt * 16 + g * 4 + e;
                if (l < 63) {
                    int r3 = (l >= 42) ? 2 : ((l >= 21) ? 1 : 0);
                    int rr = l - 21 * r3;
                    float wgt = bfu2f((rr < 20) ? Wfb16[rr * 384 + c] : Wfb16[7680 + c]);
                    p3[r3] += wgt * acc2[rt][e];
                }
            }
        }
        #pragma unroll
        for (int r3 = 0; r3 < 3; ++r3) {
            p3[r3] += __shfl_xor(p3[r3], 16, 64);
            p3[r3] += __shfl_xor(p3[r3], 32, 64);
        }
    }
    float pq[4];
    #pragma unroll
    for (int ci = 0; ci < 4; ++ci) {
        const int cwf = (w < 2) ? colR[ci] : (256 + ((colR[ci] - 256) & 127));
        float p = 0.f;
        #pragma unroll
        for (int rt = 0; rt < 2; ++rt) {
            #pragma unroll
            for (int e = 0; e < 4; ++e) {
                int row = rt * 16 + g * 4 + e;
                if (row <= 20) {
                    float wgt = bfu2f((row < 20) ? Wfb16[row * 384 + cwf] : Wfb16[7680 + cwf]);
                    p += wgt * accR[ci][rt][e];
                }
            }
        }
        p += __shfl_xor(p, 16, 64);
        p += __shfl_xor(p, 32, 64);
        pq[ci] = p;
    }
    const float vpre = (t < 384) ? v_all[(long)bi * 384 + t] : 0.f;
    __syncthreads();   // A16 dead from here; aliased writes below are safe

    // ---- aliased LDS buffers on A16 (12672 f32 available) ----
    float* fb      = (float*)A16;
    float* dmuR_s  = fb;           // 384
    float* dmumu_s = fb + 384;     // 384
    float* q_s     = fb + 768;     // 128
    float* mu_s    = fb + 896;     // 384 (16B aligned)
    float* part    = fb + 1280;    // [2][768]
    float* muV     = fb + 2816;    // 384
    float* muW     = fb + 3200;    // 384
    float* ctx     = fb + 3584;    // 256 (16B aligned)
    float* o_part  = fb + 3840;    // [2][256]
    float* hsm     = fb + 4352;    // 128 (16B aligned)
    float* x2s     = fb + 4480;    // 384
    float* red     = fb + 4864;    // 8

    if (lane < 16) {
        #pragma unroll
        for (int r3 = 0; r3 < 3; ++r3) dmuR_s[r3 * 128 + 16 * w + l16] = p3[r3];
        #pragma unroll
        for (int ci = 0; ci < 4; ++ci) {
            if (w < 2) {
                q_s[colR[ci]] = s_all[bi * 128 + colR[ci]] + pq[ci];
            } else {
                dmumu_s[colR[ci] - 256] = pq[ci];
            }
        }
    }
    __syncthreads();
    if (t < 384) mu_s[t] = vpre + dmuR_s[t] + dmumu_s[t];
    __syncthreads();

    // ================= Phase C: mixing (uint2 weights, float4 LDS reads) =================
    const int c = t & 255, kh = t >> 8;
    float qv = (t < 128) ? q_s[t] : 0.f;

    {
        float m0 = 0.f, m1 = 0.f, m2 = 0.f;
        const int k40 = kh * 16;
        #pragma unroll 4
        for (int k4 = k40; k4 < k40 + 16; ++k4) {
            uint2 u = *(const uint2*)&Wmu_p[k4 * 512 + c * 2];
            const int k = 4 * k4;
            float4 a0 = *(const float4*)&mu_s[k];
            float4 a1 = *(const float4*)&mu_s[128 + k];
            float4 a2 = *(const float4*)&mu_s[256 + k];
            float w0 = lo2f(u.x), w1 = hi2f(u.x), w2 = lo2f(u.y), w3 = hi2f(u.y);
            m0 += a0.x * w0 + a0.y * w1 + a0.z * w2 + a0.w * w3;
            m1 += a1.x * w0 + a1.y * w1 + a1.z * w2 + a1.w * w3;
            m2 += a2.x * w0 + a2.y * w1 + a2.z * w2 + a2.w * w3;
        }
        part[kh * 768 + c] = m0; part[kh * 768 + 256 + c] = m1; part[kh * 768 + 512 + c] = m2;
    }
    float ss = qv * qv;
    #pragma unroll
    for (int off = 32; off > 0; off >>= 1) ss += __shfl_xor(ss, off, 64);
    if ((t & 63) == 0) red[t >> 6] = ss;
    __syncthreads();
    for (int idx = t; idx < 768; idx += 512) {
        const int r3 = idx >> 8, cc = idx & 255;
        float val = part[idx] + part[768 + idx];
        if (cc < 128) muV[r3 * 128 + cc] = val;
        else          muW[r3 * 128 + (cc - 128)] = val;
    }
    __syncthreads();
    float mean = (red[0] + red[1] + red[2] + red[3] + red[4] + red[5] + red[6] + red[7])
                 * (1.0f / 128.0f);
    if (t < 128) {
        ctx[t] = qv * rsqrtf(mean + 1e-6f) * (1.0f + norm2_w[t]);
    } else if (t < 256) {
        int d2 = t - 128;
        ctx[t] = sqrtf(muV[d2] * muV[d2] + muV[128 + d2] * muV[128 + d2]
                       + muV[256 + d2] * muV[256 + d2] + 1e-6f);
    }
    __syncthreads();

    {
        float acc0 = 0.f, acc1 = 0.f;
        const int k40 = kh * 32;
        #pragma unroll 8
        for (int k4 = k40; k4 < k40 + 32; ++k4) {
            uint2 u = *(const uint2*)&Wm1_p[k4 * 512 + c * 2];
            float4 cx = *(const float4*)&ctx[4 * k4];
            acc0 += cx.x * lo2f(u.x) + cx.y * hi2f(u.x);
            acc1 += cx.z * lo2f(u.y) + cx.w * hi2f(u.y);
        }
        o_part[kh * 256 + c] = acc0 + acc1;
    }
    __syncthreads();
    if (t < 128) {
        float a  = o_part[t]       + o_part[256 + t]       + b_m1[t];
        float gg = o_part[t + 128] + o_part[256 + t + 128] + b_m1[t + 128];
        hsm[t] = a * sigm(a) * sigm(gg);
    }
    __syncthreads();
    if (t < 384) {
        float a0 = b_m2[t], a1 = 0.f;
        #pragma unroll 8
        for (int k4 = 0; k4 < 32; ++k4) {
            uint2 u = *(const uint2*)&Wm2_p[k4 * 768 + t * 2];
            float4 hx = *(const float4*)&hsm[4 * k4];
            a0 += hx.x * lo2f(u.x) + hx.y * hi2f(u.x);
            a1 += hx.z * lo2f(u.y) + hx.w * hi2f(u.y);
        }
        x2s[t] = a0 + a1;
    }
    __syncthreads();

    if (t < 128) {
        const int d = t;
        float vw = muV[d] * muW[d] + muV[128 + d] * muW[128 + d] + muV[256 + d] * muW[256 + d];
        if (i < 192)
            q_out[((long)b * 192 + i) * 128 + d] = qv + x2s[d] + x2s[256 + d] * vw;
        #pragma unroll
        for (int r = 0; r < 3; ++r)
            mu_out[((long)bi * 3 + r) * 128 + d] =
                mu_s[r * 128 + d] + x2s[128 + d] * muW[r * 128 + d];
    }
}

extern "C" void kernel_launch(void* const* d_in, const int* in_sizes, int n_in,
                              void* d_out, int out_size, void* d_ws, size_t ws_size,
                              hipStream_t stream) {
    (void)in_sizes; (void)n_in; (void)out_size;
    const float* s_heavy  = (const float*)d_in[0];
    const float* v_all    = (const float*)d_in[1];
    const float* rbf      = (const float*)d_in[2];
    const float* dir_ij   = (const float*)d_in[3];
    const float* mask_ij  = (const float*)d_in[4];
    const int*   is_h     = (const int*)d_in[5];
    const float* h_emb    = (const float*)d_in[6];
    const float* W_filter = (const float*)d_in[7];
    const float* b_filter = (const float*)d_in[8];
    const float* norm1_w  = (const float*)d_in[9];
    const float* W_i1     = (const float*)d_in[10];
    const float* b_i1     = (const float*)d_in[11];
    const float* W_i2     = (const float*)d_in[12];
    const float* b_i2     = (const float*)d_in[13];
    const float* norm2_w  = (const float*)d_in[14];
    const float* W_m1     = (const float*)d_in[15];
    const float* b_m1     = (const float*)d_in[16];
    const float* W_m2     = (const float*)d_in[17];
    const float* b_m2     = (const float*)d_in[18];
    const float* W_mu     = (const float*)d_in[19];

    // ws layout (f32 units): s_all 0 | Bg 65536(+163840) | Wmu_p 229376(+16384)
    //  | Wm1_p 245760(+32768) | Wm2_p 278528(+24576) | Wfb_p 303104(+4032)
    const size_t need = (size_t)307136 * 4;
    if (ws_size < need) return;
    float* ws    = (float*)d_ws;
    float* s_all = ws;
    unsigned* Bg    = (unsigned*)(ws + 65536);
    unsigned* Wmu_p = (unsigned*)(ws + 229376);
    unsigned* Wm1_p = (unsigned*)(ws + 245760);
    unsigned* Wm2_p = (unsigned*)(ws + 278528);
    unsigned* Wfb_p = (unsigned*)(ws + 303104);

    float* q_out  = (float*)d_out;               // (2,192,128)
    float* mu_out = q_out + 2 * 192 * 128;       // (2,256,3,128)

    kA<<<544, 512, 0, stream>>>(s_heavy, is_h, h_emb, norm1_w, W_i1, b_i1, W_i2, b_i2,
                                W_mu, W_m1, W_m2, W_filter, b_filter, v_all,
                                s_all, (unsigned short*)Bg,
                                Wmu_p, Wm1_p, Wm2_p, Wfb_p);
    kBC<<<512, 512, 0, stream>>>(rbf, dir_ij, mask_ij, v_all, s_all, Bg,
                                 Wmu_p, norm2_w, Wm1_p, b_m1, Wm2_p, b_m2, Wfb_p,
                                 q_out, mu_out);
}